// Round 1
// baseline (11180.778 us; speedup 1.0000x reference)
//
#include <hip/hip_runtime.h>
#include <hip/hip_cooperative_groups.h>

namespace cg = cooperative_groups;

// ---------- types / helpers ----------
typedef short s16x8 __attribute__((ext_vector_type(8)));   // 8 bf16 (4 VGPRs) MFMA A/B frag
typedef float f32x4 __attribute__((ext_vector_type(4)));   // MFMA C/D frag

#define MFMA_B16(a, b, c) __builtin_amdgcn_mfma_f32_16x16x32_bf16((a), (b), (c), 0, 0, 0)

__device__ __forceinline__ unsigned short f2b(float f) {   // fp32 -> bf16 RNE
    unsigned u = __builtin_bit_cast(unsigned, f);
    u = (u + 0x7fffu + ((u >> 16) & 1u)) >> 16;
    return (unsigned short)u;
}
__device__ __forceinline__ float b2f(unsigned short h) {
    unsigned u = ((unsigned)h) << 16;
    return __builtin_bit_cast(float, u);
}
__device__ __forceinline__ float sigm(float x) { return 1.f / (1.f + __expf(-x)); }
__device__ __forceinline__ float tanh_f(float x) {
    float t = __expf(-2.f * fabsf(x));
    float r = (1.f - t) / (1.f + t);
    return copysignf(r, x);
}

// Sizes: B=64 T=80 F=4096 Wd=6000 H=512 G=3H=1536 L=32
// probs: (64, 32, 6000) row-major; loss at flat index 12288000.

// ---------- micro-GEMM helpers (16x16x32 bf16 MFMA, frags direct from global/L2) ----------
// A: 64x512 bf16 row-major (rows m0..m0+15 used). W: rows (gate*512 + j0 + n)*512 bf16.
// C/D layout: col = lane&15, row = (lane>>4)*4 + reg  [doc-verified m89/m91]
__device__ __forceinline__ void mm3(const unsigned short* __restrict__ A, int m0,
                                    const unsigned short* __restrict__ W, int j0, int lane,
                                    f32x4& a0, f32x4& a1, f32x4& a2) {
    const int quad = lane >> 4, l15 = lane & 15;
    const s16x8* ap = (const s16x8*)(A + (size_t)(m0 + l15) * 512 + quad * 8);
    const s16x8* w0 = (const s16x8*)(W + (size_t)(j0 + l15) * 512 + quad * 8);
    const s16x8* w1 = (const s16x8*)(W + (size_t)(512 + j0 + l15) * 512 + quad * 8);
    const s16x8* w2 = (const s16x8*)(W + (size_t)(1024 + j0 + l15) * 512 + quad * 8);
#pragma unroll
    for (int c = 0; c < 16; ++c) {
        s16x8 a = ap[c * 4];
        a0 = MFMA_B16(a, w0[c * 4], a0);
        a1 = MFMA_B16(a, w1[c * 4], a1);
        a2 = MFMA_B16(a, w2[c * 4], a2);
    }
}

// Two A sources (gi-part A0 x W0, gh-part A1 x W1); r,z summed, n-gate parts kept separate.
__device__ __forceinline__ void mm6(const unsigned short* __restrict__ A0,
                                    const unsigned short* __restrict__ A1, int m0,
                                    const unsigned short* __restrict__ W0,
                                    const unsigned short* __restrict__ W1, int j0, int lane,
                                    f32x4& aR, f32x4& aZ, f32x4& aIN, f32x4& aHN) {
    const int quad = lane >> 4, l15 = lane & 15;
    const s16x8* a0p = (const s16x8*)(A0 + (size_t)(m0 + l15) * 512 + quad * 8);
    const s16x8* a1p = (const s16x8*)(A1 + (size_t)(m0 + l15) * 512 + quad * 8);
    const s16x8* w0r = (const s16x8*)(W0 + (size_t)(j0 + l15) * 512 + quad * 8);
    const s16x8* w0z = (const s16x8*)(W0 + (size_t)(512 + j0 + l15) * 512 + quad * 8);
    const s16x8* w0n = (const s16x8*)(W0 + (size_t)(1024 + j0 + l15) * 512 + quad * 8);
    const s16x8* w1r = (const s16x8*)(W1 + (size_t)(j0 + l15) * 512 + quad * 8);
    const s16x8* w1z = (const s16x8*)(W1 + (size_t)(512 + j0 + l15) * 512 + quad * 8);
    const s16x8* w1n = (const s16x8*)(W1 + (size_t)(1024 + j0 + l15) * 512 + quad * 8);
#pragma unroll
    for (int c = 0; c < 16; ++c) {
        s16x8 x0 = a0p[c * 4], x1 = a1p[c * 4];
        aR = MFMA_B16(x0, w0r[c * 4], aR);
        aR = MFMA_B16(x1, w1r[c * 4], aR);
        aZ = MFMA_B16(x0, w0z[c * 4], aZ);
        aZ = MFMA_B16(x1, w1z[c * 4], aZ);
        aIN = MFMA_B16(x0, w0n[c * 4], aIN);
        aHN = MFMA_B16(x1, w1n[c * 4], aHN);
    }
}

__device__ __forceinline__ void mm1(const unsigned short* __restrict__ A, int m0,
                                    const unsigned short* __restrict__ W, int w0, int lane,
                                    f32x4& acc) {
    const int quad = lane >> 4, l15 = lane & 15;
    const s16x8* ap = (const s16x8*)(A + (size_t)(m0 + l15) * 512 + quad * 8);
    const s16x8* wp = (const s16x8*)(W + (size_t)(w0 + l15) * 512 + quad * 8);
#pragma unroll
    for (int c = 0; c < 16; ++c) acc = MFMA_B16(ap[c * 4], wp[c * 4], acc);
}

// ---------- prep: weight bf16 conversion, state zeroing, probs row-0 ----------
__global__ void prep_kernel(const float* __restrict__ Whh_v, const float* __restrict__ Whh_c,
                            const float* __restrict__ Wih_c, const float* __restrict__ Wout,
                            unsigned short* __restrict__ WhhvB, unsigned short* __restrict__ WhhcB,
                            unsigned short* __restrict__ WchhB, unsigned short* __restrict__ WoutB,
                            unsigned short* __restrict__ zeroB, unsigned short* __restrict__ hcb0,
                            float* __restrict__ hvf, float* __restrict__ hcf,
                            float* __restrict__ out) {
    const int n = gridDim.x * blockDim.x;
    const int id0 = blockIdx.x * blockDim.x + threadIdx.x;
    for (int i = id0; i < 786432; i += n) {
        WhhvB[i] = f2b(Whh_v[i]);
        WhhcB[i] = f2b(Whh_c[i]);
        WchhB[i] = f2b(Wih_c[(size_t)(i >> 9) * 6512 + (i & 511)]);  // Wih_c[:, :512] packed
    }
    for (int i = id0; i < 3072000; i += n) WoutB[i] = f2b(Wout[i]);
    for (int i = id0; i < 384000; i += n)  // probs[:,0,:] = 0 except probs[0,0,1]=1
        out[(size_t)(i / 6000) * 192000 + (i % 6000)] = (i == 1) ? 1.f : 0.f;
    for (int i = id0; i < 32768; i += n) {
        zeroB[i] = 0; hcb0[i] = 0; hvf[i] = 0.f; hcf[i] = 0.f;
    }
}

// ---------- transpose Wih_c[:, 512:] -> WcwT (6000 x 1536) bf16, LDS-tiled ----------
__global__ void transpose_kernel(const float* __restrict__ Wc, unsigned short* __restrict__ WT) {
    __shared__ float tile[64][65];
    const int g0 = blockIdx.x * 64;   // 24 tiles over 1536
    const int w0 = blockIdx.y * 64;   // 94 tiles over 6000
    const int tx = threadIdx.x & 63;
    const int ty = threadIdx.x >> 6;
    for (int r = ty; r < 64; r += 4) {
        int w = w0 + tx;
        tile[r][tx] = (w < 6000) ? Wc[(size_t)(g0 + r) * 6512 + 512 + w] : 0.f;
    }
    __syncthreads();
    for (int r = ty; r < 64; r += 4) {
        int w = w0 + r;
        if (w < 6000) WT[(size_t)w * 1536 + g0 + tx] = f2b(tile[tx][r]);
    }
}

// ---------- GEMM1: gi_v[t*64+b, g] = x[b,t,:] . Wih_v[g,:] + bih_v[g]  (fp32->bf16 on the fly) ----------
__global__ __launch_bounds__(256) void gemm1_kernel(const float* __restrict__ x,
                                                    const float* __restrict__ Wih,
                                                    const float* __restrict__ bih,
                                                    float* __restrict__ gi) {
    __shared__ unsigned short As[128 * 40];  // 128 x 32, stride 40 to break bank conflicts
    __shared__ unsigned short Bs[128 * 40];
    const int bm = blockIdx.x % 40;
    const int bn = blockIdx.x / 40;
    const int m0 = bm * 128, n0 = bn * 128;
    const int tid = threadIdx.x;
    const int lane = tid & 63;
    const int wave = tid >> 6;
    const int wm = (wave >> 1) * 64, wn = (wave & 1) * 64;
    const int quad = lane >> 4, l15 = lane & 15;

    const f32x4 z4 = {0.f, 0.f, 0.f, 0.f};
    f32x4 acc[4][4];
#pragma unroll
    for (int i = 0; i < 4; ++i)
#pragma unroll
        for (int j = 0; j < 4; ++j) acc[i][j] = z4;

    const int sr = tid >> 2;         // staging row 0..63
    const int sc = (tid & 3) * 8;    // staging col group

    for (int k0 = 0; k0 < 4096; k0 += 32) {
        __syncthreads();
#pragma unroll
        for (int pass = 0; pass < 2; ++pass) {
            const int r = sr + pass * 64;
            const int m = m0 + r;  // m = t*64 + b  ->  x row = b*80 + t
            const float* srcA = x + (size_t)((m & 63) * 80 + (m >> 6)) * 4096 + k0 + sc;
            float4 v0 = *(const float4*)srcA;
            float4 v1 = *(const float4*)(srcA + 4);
            s16x8 sv;
            sv[0] = (short)f2b(v0.x); sv[1] = (short)f2b(v0.y);
            sv[2] = (short)f2b(v0.z); sv[3] = (short)f2b(v0.w);
            sv[4] = (short)f2b(v1.x); sv[5] = (short)f2b(v1.y);
            sv[6] = (short)f2b(v1.z); sv[7] = (short)f2b(v1.w);
            *(s16x8*)&As[r * 40 + sc] = sv;

            const float* srcB = Wih + (size_t)(n0 + r) * 4096 + k0 + sc;
            float4 u0 = *(const float4*)srcB;
            float4 u1 = *(const float4*)(srcB + 4);
            s16x8 sw;
            sw[0] = (short)f2b(u0.x); sw[1] = (short)f2b(u0.y);
            sw[2] = (short)f2b(u0.z); sw[3] = (short)f2b(u0.w);
            sw[4] = (short)f2b(u1.x); sw[5] = (short)f2b(u1.y);
            sw[6] = (short)f2b(u1.z); sw[7] = (short)f2b(u1.w);
            *(s16x8*)&Bs[r * 40 + sc] = sw;
        }
        __syncthreads();
        s16x8 af[4], bfr[4];
#pragma unroll
        for (int i = 0; i < 4; ++i) af[i] = *(const s16x8*)&As[(wm + i * 16 + l15) * 40 + quad * 8];
#pragma unroll
        for (int j = 0; j < 4; ++j) bfr[j] = *(const s16x8*)&Bs[(wn + j * 16 + l15) * 40 + quad * 8];
#pragma unroll
        for (int i = 0; i < 4; ++i)
#pragma unroll
            for (int j = 0; j < 4; ++j) acc[i][j] = MFMA_B16(af[i], bfr[j], acc[i][j]);
    }
#pragma unroll
    for (int i = 0; i < 4; ++i)
#pragma unroll
        for (int j = 0; j < 4; ++j)
#pragma unroll
            for (int r = 0; r < 4; ++r) {
                const int m = m0 + wm + i * 16 + quad * 4 + r;
                const int n = n0 + wn + j * 16 + l15;
                gi[(size_t)m * 1536 + n] = acc[i][j][r] + bih[n];
            }
}

// ---------- persistent cooperative kernel: scans + decoder + logits + loss ----------
struct SeqParams {
    const float* bih_v; const float* bhh_v;
    const float* bih_c; const float* bhh_c;
    const float* bout;  const int* y;
    const float* gi;    float* out;
    const unsigned short* WhhvB; const unsigned short* WhhcB; const unsigned short* WchhB;
    const unsigned short* WoutB; const unsigned short* WcwTB;
    unsigned short* eo; unsigned short* hcb0; unsigned short* hcb1;
    unsigned short* hcdB; unsigned short* zeroB;
    float* hvf; float* hcf; float* lossP;
};

__global__ __launch_bounds__(256, 2) void seq_kernel(SeqParams p) {
    cg::grid_group grid = cg::this_grid();
    const int lane = threadIdx.x & 63;
    const int wu = (blockIdx.x << 2) | (threadIdx.x >> 6);
    const int WU = gridDim.x << 2;
    const int half = WU >> 1;
    const int quad = lane >> 4, l15 = lane & 15;
    const f32x4 z4 = {0.f, 0.f, 0.f, 0.f};

    // ===== encoder: iteration t runs enc_v step t (t<80) and enc_c step t-1 (t>=1) =====
    for (int t = 0; t <= 80; ++t) {
        if (t < 80 && wu < half) {
            for (int it = wu; it < 128; it += half) {
                const int m0 = (it >> 5) << 4;
                const int j0 = (it & 31) << 4;
                const unsigned short* A = (t == 0) ? p.zeroB : (p.eo + (size_t)(t - 1) * 32768);
                f32x4 aR = z4, aZ = z4, aN = z4;
                mm3(A, m0, p.WhhvB, j0, lane, aR, aZ, aN);
                const float* giv = p.gi + (size_t)t * 98304;
                unsigned short* eoW = p.eo + (size_t)t * 32768;
#pragma unroll
                for (int r = 0; r < 4; ++r) {
                    const int b = m0 + quad * 4 + r;
                    const int j = j0 + l15;
                    const float* gb = giv + b * 1536;
                    float rg = sigm(gb[j] + aR[r] + p.bhh_v[j]);
                    float zg = sigm(gb[512 + j] + aZ[r] + p.bhh_v[512 + j]);
                    float ng = tanh_f(gb[1024 + j] + rg * (aN[r] + p.bhh_v[1024 + j]));
                    float hp = p.hvf[b * 512 + j];
                    float hn = (1.f - zg) * ng + zg * hp;
                    p.hvf[b * 512 + j] = hn;
                    eoW[b * 512 + j] = f2b(hn);
                }
            }
        }
        if (t >= 1 && wu >= half) {
            const int tc = t - 1;
            const unsigned short* hcbR = (tc & 1) ? p.hcb1 : p.hcb0;
            unsigned short* hcbW = (tc & 1) ? p.hcb0 : p.hcb1;
            const unsigned short* eoA = p.eo + (size_t)tc * 32768;
            for (int it = wu - half; it < 128; it += half) {
                const int m0 = (it >> 5) << 4;
                const int j0 = (it & 31) << 4;
                f32x4 aR = z4, aZ = z4, aIN = z4, aHN = z4;
                mm6(eoA, hcbR, m0, p.WchhB, p.WhhcB, j0, lane, aR, aZ, aIN, aHN);
#pragma unroll
                for (int r = 0; r < 4; ++r) {
                    const int b = m0 + quad * 4 + r;
                    const int j = j0 + l15;
                    float rg = sigm(aR[r] + p.bih_c[j] + p.bhh_c[j]);
                    float zg = sigm(aZ[r] + p.bih_c[512 + j] + p.bhh_c[512 + j]);
                    float ng = tanh_f(aIN[r] + p.bih_c[1024 + j] +
                                      rg * (aHN[r] + p.bhh_c[1024 + j]));
                    float hp = p.hcf[b * 512 + j];
                    float hn = (1.f - zg) * ng + zg * hp;
                    p.hcf[b * 512 + j] = hn;
                    hcbW[b * 512 + j] = f2b(hn);
                }
            }
        }
        grid.sync();
    }

    // ===== decoder: 32 iterations, 2 syncs each =====
    for (int s = 0; s <= 31; ++s) {
        // phase A: h_v2 update (s<=30) on low half; logits of step s-1 (s>=1) on high half
        if (s <= 30 && wu < half) {
            const unsigned short* gB = (s & 1) ? p.hcb1 : p.hcb0;
            unsigned short* gW = (s & 1) ? p.hcb0 : p.hcb1;
            for (int it = wu; it < 128; it += half) {
                const int m0 = (it >> 5) << 4;
                const int j0 = (it & 31) << 4;
                f32x4 aR = z4, aZ = z4, aN = z4;
                mm3(gB, m0, p.WhhvB, j0, lane, aR, aZ, aN);
#pragma unroll
                for (int r = 0; r < 4; ++r) {
                    const int b = m0 + quad * 4 + r;
                    const int j = j0 + l15;
                    float rg = sigm(p.bih_v[j] + aR[r] + p.bhh_v[j]);
                    float zg = sigm(p.bih_v[512 + j] + aZ[r] + p.bhh_v[512 + j]);
                    float ng = tanh_f(p.bih_v[1024 + j] + rg * (aN[r] + p.bhh_v[1024 + j]));
                    float hp = p.hcf[b * 512 + j];
                    float hn = (1.f - zg) * ng + zg * hp;
                    p.hcf[b * 512 + j] = hn;
                    gW[b * 512 + j] = f2b(hn);
                }
            }
        }
        if (s >= 1 && wu >= half) {
            for (int it = wu - half; it < 1500; it += half) {
                const int m0 = (it & 3) << 4;
                const int w0 = (it >> 2) << 4;
                f32x4 acc = z4;
                mm1(p.hcdB, m0, p.WoutB, w0, lane, acc);
#pragma unroll
                for (int r = 0; r < 4; ++r) {
                    const int b = m0 + quad * 4 + r;
                    const int wc = w0 + l15;
                    p.out[(size_t)b * 192000 + (size_t)s * 6000 + wc] = acc[r] + p.bout[wc];
                }
            }
        }
        grid.sync();
        // phase B: h_c of step s (s<=30) from h_v2 (+ embedding of y[s])
        if (s <= 30) {
            const unsigned short* g2 = ((s + 1) & 1) ? p.hcb1 : p.hcb0;
            for (int it = wu; it < 128; it += WU) {
                const int m0 = (it >> 5) << 4;
                const int j0 = (it & 31) << 4;
                f32x4 aR = z4, aZ = z4, aIN = z4, aHN = z4;
                mm6(g2, g2, m0, p.WchhB, p.WhhcB, j0, lane, aR, aZ, aIN, aHN);
#pragma unroll
                for (int r = 0; r < 4; ++r) {
                    const int b = m0 + quad * 4 + r;
                    const int j = j0 + l15;
                    const int yv = p.y[s * 64 + b];
                    const unsigned short* em = p.WcwTB + (size_t)yv * 1536;
                    float er = b2f(em[j]), ez = b2f(em[512 + j]), en = b2f(em[1024 + j]);
                    float rg = sigm(aR[r] + er + p.bih_c[j] + p.bhh_c[j]);
                    float zg = sigm(aZ[r] + ez + p.bih_c[512 + j] + p.bhh_c[512 + j]);
                    float ng = tanh_f(aIN[r] + en + p.bih_c[1024 + j] +
                                      rg * (aHN[r] + p.bhh_c[1024 + j]));
                    float h2 = p.hcf[b * 512 + j];  // h = h_v2 for this GRU
                    p.hcdB[b * 512 + j] = f2b((1.f - zg) * ng + zg * h2);
                }
            }
        }
        grid.sync();
    }

    // ===== loss: -mean_b log_softmax(logits[-1])[y[-1]] =====
    for (int it = wu; it < 64; it += WU) {
        const float* lg = p.out + (size_t)it * 192000 + 186000;  // row (b=it, l=31)
        float m = -1e30f, sum = 0.f;
        for (int wv = lane; wv < 6000; wv += 64) {
            float v = lg[wv];
            float nm = fmaxf(m, v);
            sum = sum * __expf(m - nm) + __expf(v - nm);
            m = nm;
        }
#pragma unroll
        for (int off = 32; off > 0; off >>= 1) {
            float m2 = __shfl_down(m, off);
            float s2 = __shfl_down(sum, off);
            float nm = fmaxf(m, m2);
            sum = sum * __expf(m - nm) + s2 * __expf(m2 - nm);
            m = nm;
        }
        if (lane == 0) {
            int yv = p.y[31 * 64 + it];
            p.lossP[it] = (m + __logf(sum)) - lg[yv];
        }
    }
    grid.sync();
    if (wu == 0) {
        float v = p.lossP[lane];
#pragma unroll
        for (int off = 32; off > 0; off >>= 1) v += __shfl_down(v, off);
        if (lane == 0) p.out[12288000] = v * (1.f / 64.f);
    }
}

// ---------- host ----------
extern "C" void kernel_launch(void* const* d_in, const int* in_sizes, int n_in,
                              void* d_out, int out_size, void* d_ws, size_t ws_size,
                              hipStream_t stream) {
    const float* x     = (const float*)d_in[0];
    const int*   y     = (const int*)d_in[1];
    const float* Wih_v = (const float*)d_in[2];
    const float* Whh_v = (const float*)d_in[3];
    const float* bih_v = (const float*)d_in[4];
    const float* bhh_v = (const float*)d_in[5];
    const float* Wih_c = (const float*)d_in[6];
    const float* Whh_c = (const float*)d_in[7];
    const float* bih_c = (const float*)d_in[8];
    const float* bhh_c = (const float*)d_in[9];
    const float* Wout  = (const float*)d_in[10];
    const float* bout  = (const float*)d_in[11];
    float* out = (float*)d_out;

    char* w = (char*)d_ws;
    size_t o = 0;
    auto alloc = [&](size_t bytes) -> void* {
        void* p = (void*)(w + o);
        o += (bytes + 255) & ~(size_t)255;
        return p;
    };
    float*          gi    = (float*)alloc(7864320ull * 4);          // gi_v (T,B,3H) fp32
    unsigned short* WhhvB = (unsigned short*)alloc(786432ull * 2);
    unsigned short* WhhcB = (unsigned short*)alloc(786432ull * 2);
    unsigned short* WchhB = (unsigned short*)alloc(786432ull * 2);  // Wih_c[:, :512] bf16
    unsigned short* WoutB = (unsigned short*)alloc(3072000ull * 2);
    unsigned short* WcwTB = (unsigned short*)alloc(9216000ull * 2); // (6000,1536) bf16
    unsigned short* eo    = (unsigned short*)alloc(2621440ull * 2); // enc_out bf16 (80,64,512)
    unsigned short* hcb0  = (unsigned short*)alloc(32768ull * 2);
    unsigned short* hcb1  = (unsigned short*)alloc(32768ull * 2);
    unsigned short* hcdB  = (unsigned short*)alloc(32768ull * 2);
    unsigned short* zeroB = (unsigned short*)alloc(32768ull * 2);
    float*          hvf   = (float*)alloc(32768ull * 4);
    float*          hcf   = (float*)alloc(32768ull * 4);
    float*          lossP = (float*)alloc(64ull * 4);
    if (o > ws_size) return;  // insufficient scratch; avoid OOB writes

    prep_kernel<<<512, 256, 0, stream>>>(Whh_v, Whh_c, Wih_c, Wout, WhhvB, WhhcB, WchhB, WoutB,
                                         zeroB, hcb0, hvf, hcf, out);
    transpose_kernel<<<dim3(24, 94), 256, 0, stream>>>(Wih_c, WcwTB);
    gemm1_kernel<<<480, 256, 0, stream>>>(x, Wih_v, bih_v, gi);

    SeqParams p;
    p.bih_v = bih_v; p.bhh_v = bhh_v; p.bih_c = bih_c; p.bhh_c = bhh_c;
    p.bout = bout; p.y = y; p.gi = gi; p.out = out;
    p.WhhvB = WhhvB; p.WhhcB = WhhcB; p.WchhB = WchhB; p.WoutB = WoutB; p.WcwTB = WcwTB;
    p.eo = eo; p.hcb0 = hcb0; p.hcb1 = hcb1; p.hcdB = hcdB; p.zeroB = zeroB;
    p.hvf = hvf; p.hcf = hcf; p.lossP = lossP;
    void* args[] = {&p};
    hipLaunchCooperativeKernel((void*)seq_kernel, dim3(512), dim3(256), args, 0, stream);
}

// Round 2
// 3708.755 us; speedup vs baseline: 3.0147x; 3.0147x over previous
//
#include <hip/hip_runtime.h>

// ---------- types / helpers ----------
typedef short s16x8 __attribute__((ext_vector_type(8)));   // 8 bf16 (4 VGPRs) MFMA A/B frag
typedef float f32x4 __attribute__((ext_vector_type(4)));   // MFMA C/D frag

#define MFMA_B16(a, b, c) __builtin_amdgcn_mfma_f32_16x16x32_bf16((a), (b), (c), 0, 0, 0)
#define LDS_PAD 520  // 512 + 8 shorts: row stride 1040 B -> 2-way bank aliasing only (free)

__device__ __forceinline__ unsigned short f2b(float f) {   // fp32 -> bf16 RNE
    unsigned u = __builtin_bit_cast(unsigned, f);
    u = (u + 0x7fffu + ((u >> 16) & 1u)) >> 16;
    return (unsigned short)u;
}
__device__ __forceinline__ float b2f(unsigned short h) {
    unsigned u = ((unsigned)h) << 16;
    return __builtin_bit_cast(float, u);
}
__device__ __forceinline__ float sigm(float x) { return 1.f / (1.f + __expf(-x)); }
__device__ __forceinline__ float tanh_f(float x) {
    float t = __expf(-2.f * fabsf(x));
    float r = (1.f - t) / (1.f + t);
    return copysignf(r, x);
}

// ---------- sync primitives (agent scope; per-XCD L2 non-coherent -> device-scope atomics) ----------
__device__ __forceinline__ void group_barrier(int* ctr, int target) {
    __syncthreads();
    if (threadIdx.x == 0) {
        __threadfence();
        __hip_atomic_fetch_add(ctr, 1, __ATOMIC_RELEASE, __HIP_MEMORY_SCOPE_AGENT);
        while (__hip_atomic_load(ctr, __ATOMIC_ACQUIRE, __HIP_MEMORY_SCOPE_AGENT) < target)
            __builtin_amdgcn_s_sleep(1);
    }
    __syncthreads();
}
__device__ __forceinline__ void wait_ctr(int* ctr, int target) {
    __syncthreads();
    if (threadIdx.x == 0) {
        while (__hip_atomic_load(ctr, __ATOMIC_ACQUIRE, __HIP_MEMORY_SCOPE_AGENT) < target)
            __builtin_amdgcn_s_sleep(1);
    }
    __syncthreads();
}
__device__ __forceinline__ void signal_ctr(int* ctr) {
    __syncthreads();
    if (threadIdx.x == 0) {
        __threadfence();
        __hip_atomic_fetch_add(ctr, 1, __ATOMIC_RELEASE, __HIP_MEMORY_SCOPE_AGENT);
    }
}

// ---------- LDS staging: nrows x 512 bf16, padded row stride ----------
__device__ __forceinline__ void stage_rows(const unsigned short* __restrict__ g,
                                           unsigned short* l, int nrows) {
    for (int idx = threadIdx.x; idx < nrows * 64; idx += 256) {
        const int r = idx >> 6, c = (idx & 63) * 8;
        *(uint4*)(l + r * LDS_PAD + c) = *(const uint4*)(g + (size_t)r * 512 + c);
    }
}

// ---------- micro-GEMMs: 16x16x32 bf16 MFMA; A from global (L2), W from LDS / L2 ----------
// C/D layout: col = lane&15, row = (lane>>4)*4 + reg
__device__ __forceinline__ void mm3_lds(const unsigned short* __restrict__ A, int m0,
                                        const unsigned short* Wl, int lane,
                                        f32x4& a0, f32x4& a1, f32x4& a2) {
    const int quad = lane >> 4, l15 = lane & 15;
    const s16x8* ap = (const s16x8*)(A + (size_t)(m0 + l15) * 512 + quad * 8);
    const unsigned short* w0 = Wl + l15 * LDS_PAD + quad * 8;
    const unsigned short* w1 = Wl + (16 + l15) * LDS_PAD + quad * 8;
    const unsigned short* w2 = Wl + (32 + l15) * LDS_PAD + quad * 8;
#pragma unroll
    for (int c = 0; c < 16; ++c) {
        s16x8 a = ap[c * 4];
        a0 = MFMA_B16(a, *(const s16x8*)(w0 + c * 32), a0);
        a1 = MFMA_B16(a, *(const s16x8*)(w1 + c * 32), a1);
        a2 = MFMA_B16(a, *(const s16x8*)(w2 + c * 32), a2);
    }
}

// gi-part (A0 x Wg[global]) -> r,z,in ; hidden-part (A1 x Wl[LDS]) -> r,z,hn
__device__ __forceinline__ void mm6_mix(const unsigned short* __restrict__ A0,
                                        const unsigned short* __restrict__ A1, int m0,
                                        const unsigned short* __restrict__ Wg, int j0,
                                        const unsigned short* Wl, int lane,
                                        f32x4& aR, f32x4& aZ, f32x4& aIN, f32x4& aHN) {
    const int quad = lane >> 4, l15 = lane & 15;
    const s16x8* a0p = (const s16x8*)(A0 + (size_t)(m0 + l15) * 512 + quad * 8);
    const s16x8* a1p = (const s16x8*)(A1 + (size_t)(m0 + l15) * 512 + quad * 8);
    const s16x8* gr = (const s16x8*)(Wg + (size_t)(j0 + l15) * 512 + quad * 8);
    const s16x8* gz = (const s16x8*)(Wg + (size_t)(512 + j0 + l15) * 512 + quad * 8);
    const s16x8* gn = (const s16x8*)(Wg + (size_t)(1024 + j0 + l15) * 512 + quad * 8);
    const unsigned short* lr = Wl + l15 * LDS_PAD + quad * 8;
    const unsigned short* lz = Wl + (16 + l15) * LDS_PAD + quad * 8;
    const unsigned short* ln = Wl + (32 + l15) * LDS_PAD + quad * 8;
#pragma unroll
    for (int c = 0; c < 16; ++c) {
        s16x8 x0 = a0p[c * 4], x1 = a1p[c * 4];
        aR = MFMA_B16(x0, gr[c * 4], aR);
        aZ = MFMA_B16(x0, gz[c * 4], aZ);
        aIN = MFMA_B16(x0, gn[c * 4], aIN);
        aR = MFMA_B16(x1, *(const s16x8*)(lr + c * 32), aR);
        aZ = MFMA_B16(x1, *(const s16x8*)(lz + c * 32), aZ);
        aHN = MFMA_B16(x1, *(const s16x8*)(ln + c * 32), aHN);
    }
}

// ---------- prep ----------
__global__ void prep_kernel(const float* __restrict__ Whh_v, const float* __restrict__ Whh_c,
                            const float* __restrict__ Wih_c, const float* __restrict__ Wout,
                            unsigned short* __restrict__ WhhvB, unsigned short* __restrict__ WhhcB,
                            unsigned short* __restrict__ WchhB, unsigned short* __restrict__ WoutB,
                            unsigned short* __restrict__ zeroB, float* __restrict__ hvf,
                            float* __restrict__ hcf, int* __restrict__ ctrs,
                            float* __restrict__ out) {
    const int n = gridDim.x * blockDim.x;
    const int id0 = blockIdx.x * blockDim.x + threadIdx.x;
    for (int i = id0; i < 786432; i += n) {
        WhhvB[i] = f2b(Whh_v[i]);
        WhhcB[i] = f2b(Whh_c[i]);
        WchhB[i] = f2b(Wih_c[(size_t)(i >> 9) * 6512 + (i & 511)]);  // Wih_c[:, :512]
    }
    for (int i = id0; i < 3072000; i += n) WoutB[i] = f2b(Wout[i]);
    for (int i = id0; i < 384000; i += n)  // probs[:,0,:] = 0 except probs[0,0,1]=1
        out[(size_t)(i / 6000) * 192000 + (i % 6000)] = (i == 1) ? 1.f : 0.f;
    for (int i = id0; i < 32768; i += n) {
        zeroB[i] = 0; hvf[i] = 0.f; hcf[i] = 0.f;
    }
    if (id0 < 16) ctrs[id0] = 0;
}

// ---------- transpose Wih_c[:, 512:] -> WcwT (6000 x 1536) bf16 ----------
__global__ void transpose_kernel(const float* __restrict__ Wc, unsigned short* __restrict__ WT) {
    __shared__ float tile[64][65];
    const int g0 = blockIdx.x * 64;
    const int w0 = blockIdx.y * 64;
    const int tx = threadIdx.x & 63;
    const int ty = threadIdx.x >> 6;
    for (int r = ty; r < 64; r += 4) {
        int w = w0 + tx;
        tile[r][tx] = (w < 6000) ? Wc[(size_t)(g0 + r) * 6512 + 512 + w] : 0.f;
    }
    __syncthreads();
    for (int r = ty; r < 64; r += 4) {
        int w = w0 + r;
        if (w < 6000) WT[(size_t)w * 1536 + g0 + tx] = f2b(tile[tx][r]);
    }
}

// ---------- GEMM1: gi_v[t*64+b, g] = x[b,t,:] . Wih_v[g,:] + bih_v[g] ----------
__global__ __launch_bounds__(256) void gemm1_kernel(const float* __restrict__ x,
                                                    const float* __restrict__ Wih,
                                                    const float* __restrict__ bih,
                                                    float* __restrict__ gi) {
    __shared__ unsigned short As[128 * 40];
    __shared__ unsigned short Bs[128 * 40];
    const int bm = blockIdx.x % 40;
    const int bn = blockIdx.x / 40;
    const int m0 = bm * 128, n0 = bn * 128;
    const int tid = threadIdx.x;
    const int lane = tid & 63;
    const int wave = tid >> 6;
    const int wm = (wave >> 1) * 64, wn = (wave & 1) * 64;
    const int quad = lane >> 4, l15 = lane & 15;

    const f32x4 z4 = {0.f, 0.f, 0.f, 0.f};
    f32x4 acc[4][4];
#pragma unroll
    for (int i = 0; i < 4; ++i)
#pragma unroll
        for (int j = 0; j < 4; ++j) acc[i][j] = z4;

    const int sr = tid >> 2;
    const int sc = (tid & 3) * 8;

    for (int k0 = 0; k0 < 4096; k0 += 32) {
        __syncthreads();
#pragma unroll
        for (int pass = 0; pass < 2; ++pass) {
            const int r = sr + pass * 64;
            const int m = m0 + r;  // m = t*64 + b -> x row = b*80 + t
            const float* srcA = x + (size_t)((m & 63) * 80 + (m >> 6)) * 4096 + k0 + sc;
            float4 v0 = *(const float4*)srcA;
            float4 v1 = *(const float4*)(srcA + 4);
            s16x8 sv;
            sv[0] = (short)f2b(v0.x); sv[1] = (short)f2b(v0.y);
            sv[2] = (short)f2b(v0.z); sv[3] = (short)f2b(v0.w);
            sv[4] = (short)f2b(v1.x); sv[5] = (short)f2b(v1.y);
            sv[6] = (short)f2b(v1.z); sv[7] = (short)f2b(v1.w);
            *(s16x8*)&As[r * 40 + sc] = sv;

            const float* srcB = Wih + (size_t)(n0 + r) * 4096 + k0 + sc;
            float4 u0 = *(const float4*)srcB;
            float4 u1 = *(const float4*)(srcB + 4);
            s16x8 sw;
            sw[0] = (short)f2b(u0.x); sw[1] = (short)f2b(u0.y);
            sw[2] = (short)f2b(u0.z); sw[3] = (short)f2b(u0.w);
            sw[4] = (short)f2b(u1.x); sw[5] = (short)f2b(u1.y);
            sw[6] = (short)f2b(u1.z); sw[7] = (short)f2b(u1.w);
            *(s16x8*)&Bs[r * 40 + sc] = sw;
        }
        __syncthreads();
        s16x8 af[4], bfr[4];
#pragma unroll
        for (int i = 0; i < 4; ++i) af[i] = *(const s16x8*)&As[(wm + i * 16 + l15) * 40 + quad * 8];
#pragma unroll
        for (int j = 0; j < 4; ++j) bfr[j] = *(const s16x8*)&Bs[(wn + j * 16 + l15) * 40 + quad * 8];
#pragma unroll
        for (int i = 0; i < 4; ++i)
#pragma unroll
            for (int j = 0; j < 4; ++j) acc[i][j] = MFMA_B16(af[i], bfr[j], acc[i][j]);
    }
#pragma unroll
    for (int i = 0; i < 4; ++i)
#pragma unroll
        for (int j = 0; j < 4; ++j)
#pragma unroll
            for (int r = 0; r < 4; ++r) {
                const int m = m0 + wm + i * 16 + quad * 4 + r;
                const int n = n0 + wn + j * 16 + l15;
                gi[(size_t)m * 1536 + n] = acc[i][j][r] + bih[n];
            }
}

// ---------- persistent pipeline kernel ----------
// blocks 0..31   group_v: enc_v chain + decoder h_v2 chain + loss. Whh_v 16-col slice in LDS.
// blocks 32..63  group_c: enc_c chain + decoder h_c (no chain). Whh_c slice LDS, Wih_c_h slice L2.
// blocks 64..188 group_o: logits (48 Wout cols each in LDS), overlapped with decode chain.
// ctr[0] c_v_enc, ctr[1] c_c_enc, ctr[2] c_v_dec, ctr[3] c_c_dec, ctr[4] c_o_done, ctr[5] c_v_loss
struct SeqParams {
    const float* bih_v; const float* bhh_v;
    const float* bih_c; const float* bhh_c;
    const float* bout;  const int* y;
    const float* gi;    float* out;
    const unsigned short* WhhvB; const unsigned short* WhhcB; const unsigned short* WchhB;
    const unsigned short* WoutB; const unsigned short* WcwTB;
    unsigned short* eo;    // 80 x (64x512) bf16
    unsigned short* hv2B;  // 32 x (64x512) bf16  (hv2B[0] = bf16(hidden_video))
    unsigned short* hcdB;  // 31 x (64x512) bf16
    unsigned short* ecb0; unsigned short* ecb1; unsigned short* zeroB;
    float* hvf; float* hcf; float* lossP; int* ctr;
};

__global__ __launch_bounds__(256) void seq_kernel(SeqParams p) {
    __shared__ unsigned short Wlds[48 * LDS_PAD];  // 49,920 B
    const int blk = blockIdx.x;
    const int lane = threadIdx.x & 63;
    const int wave = threadIdx.x >> 6;
    const int quad = lane >> 4, l15 = lane & 15;
    const f32x4 z4 = {0.f, 0.f, 0.f, 0.f};
    int* ctr = p.ctr;

    if (blk < 32) {
        // ================= group_v =================
        const int j0 = blk * 16;
        const int j = j0 + l15;
        const int m0 = wave * 16;
        const int b_ = m0 + quad * 4;
#pragma unroll
        for (int g = 0; g < 3; ++g)
            stage_rows(p.WhhvB + (size_t)(g * 512 + j0) * 512, Wlds + g * 16 * LDS_PAD, 16);
        __syncthreads();
        const float bhr = p.bhh_v[j], bhz = p.bhh_v[512 + j], bhn = p.bhh_v[1024 + j];

        for (int t = 0; t < 80; ++t) {
            float gr[4], gz[4], gn[4];
            const float* gt = p.gi + (size_t)t * 98304;
#pragma unroll
            for (int r = 0; r < 4; ++r) {
                const float* gb = gt + (size_t)(b_ + r) * 1536;
                gr[r] = gb[j]; gz[r] = gb[512 + j]; gn[r] = gb[1024 + j];
            }
            f32x4 aR = z4, aZ = z4, aN = z4;
            if (t > 0) mm3_lds(p.eo + (size_t)(t - 1) * 32768, m0, Wlds, lane, aR, aZ, aN);
            unsigned short* eoW = p.eo + (size_t)t * 32768;
#pragma unroll
            for (int r = 0; r < 4; ++r) {
                float rg = sigm(gr[r] + aR[r] + bhr);
                float zg = sigm(gz[r] + aZ[r] + bhz);
                float ng = tanh_f(gn[r] + rg * (aN[r] + bhn));
                float hp = p.hvf[(b_ + r) * 512 + j];
                float hn = (1.f - zg) * ng + zg * hp;
                p.hvf[(b_ + r) * 512 + j] = hn;
                eoW[(b_ + r) * 512 + j] = f2b(hn);
            }
            group_barrier(&ctr[0], 32 * (t + 1));
        }

        wait_ctr(&ctr[1], 32 * 80);  // enc_c done: hcf + hv2B[0] valid
        const float bir = p.bih_v[j], biz = p.bih_v[512 + j], bin_ = p.bih_v[1024 + j];
        for (int s = 0; s <= 30; ++s) {
            f32x4 aR = z4, aZ = z4, aN = z4;
            mm3_lds(p.hv2B + (size_t)s * 32768, m0, Wlds, lane, aR, aZ, aN);
            unsigned short* hw = p.hv2B + (size_t)(s + 1) * 32768;
#pragma unroll
            for (int r = 0; r < 4; ++r) {
                float rg = sigm(bir + aR[r] + bhr);
                float zg = sigm(biz + aZ[r] + bhz);
                float ng = tanh_f(bin_ + rg * (aN[r] + bhn));
                float hp = (s == 0) ? p.hcf[(b_ + r) * 512 + j] : p.hvf[(b_ + r) * 512 + j];
                float hn = (1.f - zg) * ng + zg * hp;
                p.hvf[(b_ + r) * 512 + j] = hn;
                hw[(b_ + r) * 512 + j] = f2b(hn);
            }
            group_barrier(&ctr[2], 32 * (s + 1));
        }

        // ----- loss -----
        wait_ctr(&ctr[4], 125);
        {
            const int b = (blk << 2) | wave;  // 0..127; rows 0..63 active
            if (b < 64) {
                const float* lg = p.out + (size_t)b * 192000 + 31 * 6000;
                float m = -1e30f, sum = 0.f;
                for (int wv = lane; wv < 6000; wv += 64) {
                    float v = lg[wv];
                    float nm = fmaxf(m, v);
                    sum = sum * __expf(m - nm) + __expf(v - nm);
                    m = nm;
                }
#pragma unroll
                for (int off = 32; off > 0; off >>= 1) {
                    float m2 = __shfl_down(m, off);
                    float s2 = __shfl_down(sum, off);
                    float nm = fmaxf(m, m2);
                    sum = sum * __expf(m - nm) + s2 * __expf(m2 - nm);
                    m = nm;
                }
                if (lane == 0) {
                    int yv = p.y[31 * 64 + b];
                    p.lossP[b] = (m + __logf(sum)) - lg[yv];
                }
            }
        }
        group_barrier(&ctr[5], 32);
        if (blk == 0 && threadIdx.x < 64) {
            float v = p.lossP[threadIdx.x];
#pragma unroll
            for (int off = 32; off > 0; off >>= 1) v += __shfl_down(v, off);
            if (threadIdx.x == 0) p.out[12288000] = v * (1.f / 64.f);
        }
    } else if (blk < 64) {
        // ================= group_c =================
        const int j0 = (blk - 32) * 16;
        const int j = j0 + l15;
        const int m0 = wave * 16;
        const int b_ = m0 + quad * 4;
#pragma unroll
        for (int g = 0; g < 3; ++g)
            stage_rows(p.WhhcB + (size_t)(g * 512 + j0) * 512, Wlds + g * 16 * LDS_PAD, 16);
        __syncthreads();
        const float bcr = p.bih_c[j] + p.bhh_c[j];
        const float bcz = p.bih_c[512 + j] + p.bhh_c[512 + j];
        const float bin_ = p.bih_c[1024 + j];
        const float bhn = p.bhh_c[1024 + j];

        for (int t = 0; t < 80; ++t) {
            wait_ctr(&ctr[0], 32 * (t + 1));  // eo[t] ready
            const unsigned short* A1 = (t == 0) ? p.zeroB : ((t & 1) ? p.ecb1 : p.ecb0);
            f32x4 aR = z4, aZ = z4, aIN = z4, aHN = z4;
            mm6_mix(p.eo + (size_t)t * 32768, A1, m0, p.WchhB, j0, Wlds, lane, aR, aZ, aIN, aHN);
            unsigned short* ew = (t & 1) ? p.ecb0 : p.ecb1;
#pragma unroll
            for (int r = 0; r < 4; ++r) {
                float rg = sigm(aR[r] + bcr);
                float zg = sigm(aZ[r] + bcz);
                float ng = tanh_f(aIN[r] + bin_ + rg * (aHN[r] + bhn));
                float hp = p.hcf[(b_ + r) * 512 + j];
                float hn = (1.f - zg) * ng + zg * hp;
                p.hcf[(b_ + r) * 512 + j] = hn;
                unsigned short hb = f2b(hn);
                ew[(b_ + r) * 512 + j] = hb;
                if (t == 79) p.hv2B[(b_ + r) * 512 + j] = hb;  // hv2B[0]
            }
            group_barrier(&ctr[1], 32 * (t + 1));
        }

        // decoder h_c(s): consumes h_v2(s) = hv2B[s+1]; no chain between steps
        for (int s = 0; s <= 30; ++s) {
            wait_ctr(&ctr[2], 32 * (s + 1));
            const unsigned short* hv = p.hv2B + (size_t)(s + 1) * 32768;
            f32x4 aR = z4, aZ = z4, aIN = z4, aHN = z4;
            mm6_mix(hv, hv, m0, p.WchhB, j0, Wlds, lane, aR, aZ, aIN, aHN);
            unsigned short* hc = p.hcdB + (size_t)s * 32768;
#pragma unroll
            for (int r = 0; r < 4; ++r) {
                const int yv = p.y[s * 64 + (b_ + r)];
                const unsigned short* em = p.WcwTB + (size_t)yv * 1536;
                float rg = sigm(aR[r] + b2f(em[j]) + bcr);
                float zg = sigm(aZ[r] + b2f(em[512 + j]) + bcz);
                float ng = tanh_f(aIN[r] + b2f(em[1024 + j]) + bin_ + rg * (aHN[r] + bhn));
                float hp = b2f(hv[(b_ + r) * 512 + j]);
                hc[(b_ + r) * 512 + j] = f2b((1.f - zg) * ng + zg * hp);
            }
            signal_ctr(&ctr[3]);
        }
    } else {
        // ================= group_o: logits =================
        const int bo = blk - 64;          // 0..124
        const int w0 = bo * 48;           // 48 cols each; 125*48 = 6000
        stage_rows(p.WoutB + (size_t)w0 * 512, Wlds, 48);
        __syncthreads();
        const int m0 = wave * 16;
        const int b_ = m0 + quad * 4;
        float bo_[3];
#pragma unroll
        for (int tl = 0; tl < 3; ++tl) bo_[tl] = p.bout[w0 + tl * 16 + l15];

        for (int s = 0; s <= 30; ++s) {
            wait_ctr(&ctr[3], 32 * (s + 1));
            const unsigned short* A = p.hcdB + (size_t)s * 32768;
            s16x8 af[16];
#pragma unroll
            for (int c = 0; c < 16; ++c)
                af[c] = *(const s16x8*)(A + (size_t)(m0 + l15) * 512 + quad * 8 + c * 32);
#pragma unroll
            for (int tl = 0; tl < 3; ++tl) {
                const unsigned short* wl = Wlds + (tl * 16 + l15) * LDS_PAD + quad * 8;
                f32x4 acc = z4;
#pragma unroll
                for (int c = 0; c < 16; ++c)
                    acc = MFMA_B16(af[c], *(const s16x8*)(wl + c * 32), acc);
#pragma unroll
                for (int r = 0; r < 4; ++r)
                    p.out[(size_t)(b_ + r) * 192000 + (size_t)(s + 1) * 6000 + w0 + tl * 16 + l15] =
                        acc[r] + bo_[tl];
            }
        }
        signal_ctr(&ctr[4]);
    }
}

// ---------- host ----------
extern "C" void kernel_launch(void* const* d_in, const int* in_sizes, int n_in,
                              void* d_out, int out_size, void* d_ws, size_t ws_size,
                              hipStream_t stream) {
    const float* x     = (const float*)d_in[0];
    const int*   y     = (const int*)d_in[1];
    const float* Wih_v = (const float*)d_in[2];
    const float* Whh_v = (const float*)d_in[3];
    const float* bih_v = (const float*)d_in[4];
    const float* bhh_v = (const float*)d_in[5];
    const float* Wih_c = (const float*)d_in[6];
    const float* Whh_c = (const float*)d_in[7];
    const float* bih_c = (const float*)d_in[8];
    const float* bhh_c = (const float*)d_in[9];
    const float* Wout  = (const float*)d_in[10];
    const float* bout  = (const float*)d_in[11];
    float* out = (float*)d_out;

    char* w = (char*)d_ws;
    size_t o = 0;
    auto alloc = [&](size_t bytes) -> void* {
        void* p = (void*)(w + o);
        o += (bytes + 255) & ~(size_t)255;
        return p;
    };
    float*          gi    = (float*)alloc(7864320ull * 4);
    unsigned short* WhhvB = (unsigned short*)alloc(786432ull * 2);
    unsigned short* WhhcB = (unsigned short*)alloc(786432ull * 2);
    unsigned short* WchhB = (unsigned short*)alloc(786432ull * 2);
    unsigned short* WoutB = (unsigned short*)alloc(3072000ull * 2);
    unsigned short* WcwTB = (unsigned short*)alloc(9216000ull * 2);
    unsigned short* eo    = (unsigned short*)alloc(80ull * 32768 * 2);
    unsigned short* hv2B  = (unsigned short*)alloc(32ull * 32768 * 2);
    unsigned short* hcdB  = (unsigned short*)alloc(31ull * 32768 * 2);
    unsigned short* ecb0  = (unsigned short*)alloc(32768ull * 2);
    unsigned short* ecb1  = (unsigned short*)alloc(32768ull * 2);
    unsigned short* zeroB = (unsigned short*)alloc(32768ull * 2);
    float*          hvf   = (float*)alloc(32768ull * 4);
    float*          hcf   = (float*)alloc(32768ull * 4);
    float*          lossP = (float*)alloc(64ull * 4);
    int*            ctrs  = (int*)alloc(16ull * 4);
    if (o > ws_size) return;

    prep_kernel<<<512, 256, 0, stream>>>(Whh_v, Whh_c, Wih_c, Wout, WhhvB, WhhcB, WchhB, WoutB,
                                         zeroB, hvf, hcf, ctrs, out);
    transpose_kernel<<<dim3(24, 94), 256, 0, stream>>>(Wih_c, WcwTB);
    gemm1_kernel<<<480, 256, 0, stream>>>(x, Wih_v, bih_v, gi);

    SeqParams p;
    p.bih_v = bih_v; p.bhh_v = bhh_v; p.bih_c = bih_c; p.bhh_c = bhh_c;
    p.bout = bout; p.y = y; p.gi = gi; p.out = out;
    p.WhhvB = WhhvB; p.WhhcB = WhhcB; p.WchhB = WchhB; p.WoutB = WoutB; p.WcwTB = WcwTB;
    p.eo = eo; p.hv2B = hv2B; p.hcdB = hcdB;
    p.ecb0 = ecb0; p.ecb1 = ecb1; p.zeroB = zeroB;
    p.hvf = hvf; p.hcf = hcf; p.lossP = lossP; p.ctr = ctrs;
    void* args[] = {&p};
    hipLaunchCooperativeKernel((void*)seq_kernel, dim3(189), dim3(256), args, 0, stream);
}

// Round 3
// 1849.209 us; speedup vs baseline: 6.0462x; 2.0056x over previous
//
#include <hip/hip_runtime.h>

// ---------- types / helpers ----------
typedef short s16x8 __attribute__((ext_vector_type(8)));   // 8 bf16 (4 VGPRs) MFMA A/B frag
typedef float f32x4 __attribute__((ext_vector_type(4)));   // MFMA C/D frag
typedef unsigned short u16x4 __attribute__((ext_vector_type(4)));

#define MFMA_B16(a, b, c) __builtin_amdgcn_mfma_f32_16x16x32_bf16((a), (b), (c), 0, 0, 0)

__device__ __forceinline__ unsigned short f2b(float f) {   // fp32 -> bf16 RNE
    unsigned u = __builtin_bit_cast(unsigned, f);
    u = (u + 0x7fffu + ((u >> 16) & 1u)) >> 16;
    return (unsigned short)u;
}
__device__ __forceinline__ float b2f(unsigned short h) {
    unsigned u = ((unsigned)h) << 16;
    return __builtin_bit_cast(float, u);
}
__device__ __forceinline__ float sigm(float x) { return 1.f / (1.f + __expf(-x)); }
__device__ __forceinline__ float tanh_f(float x) {
    float t = __expf(-2.f * fabsf(x));
    float r = (1.f - t) / (1.f + t);
    return copysignf(r, x);
}

// ---------- coherent-bypass ops (device scope = sc1; NO cache-wide maintenance) ----------
__device__ __forceinline__ void stg_b16_sc(unsigned short* p, unsigned short v) {
    unsigned v32 = v;
    asm volatile("global_store_short %0, %1, off sc1" :: "v"(p), "v"(v32) : "memory");
}
__device__ __forceinline__ void stg_b32_sc(float* p, float v) {
    asm volatile("global_store_dword %0, %1, off sc1" :: "v"(p), "v"(v) : "memory");
}
__device__ __forceinline__ unsigned long long ldg_u64_sc(const void* p) {
    return __hip_atomic_load((unsigned long long*)p, __ATOMIC_RELAXED, __HIP_MEMORY_SCOPE_AGENT);
}
__device__ __forceinline__ float ldg_b16_sc(const unsigned short* p) {
    unsigned short v = __hip_atomic_load((unsigned short*)p, __ATOMIC_RELAXED, __HIP_MEMORY_SCOPE_AGENT);
    return b2f(v);
}
__device__ __forceinline__ float ldg_f32_sc(const float* p) {
    return __hip_atomic_load((float*)p, __ATOMIC_RELAXED, __HIP_MEMORY_SCOPE_AGENT);
}
__device__ __forceinline__ s16x8 ldA_sc(const unsigned short* p) {
    union { unsigned long long u[2]; s16x8 v; } r;
    r.u[0] = ldg_u64_sc(p);
    r.u[1] = ldg_u64_sc((const unsigned long long*)p + 1);
    return r.v;
}

// per-wave relaxed spin / signal (counters padded to 256B apart)
__device__ __forceinline__ void wave_wait(int* c, int target) {
    while (__hip_atomic_load(c, __ATOMIC_RELAXED, __HIP_MEMORY_SCOPE_AGENT) < target) {}
}
__device__ __forceinline__ void wave_signal(int* c) {
    asm volatile("s_waitcnt vmcnt(0)" ::: "memory");  // drain this wave's sc1 stores
    if ((threadIdx.x & 63) == 0)
        __hip_atomic_fetch_add(c, 1, __ATOMIC_RELAXED, __HIP_MEMORY_SCOPE_AGENT);
}

// ---------- swizzled LDS weight tiles ----------
// tile = 16 rows x 512 cols bf16, stored in MFMA-B fragment order:
// frag(c, lane) = W[row = lane&15][col = (lane>>4)*8 + c*32 .. +7]  at LDS [(c*64+lane)*8]
// -> wave ds_read_b128 is lane-contiguous 1KB: conflict-free by construction.
#define WTILE 8192  // shorts per tile
#define WF(Wl, t, c, lane) (*(const s16x8*)((Wl) + (((t) * 16 + (c)) * 64 + (lane)) * 8))

__device__ __forceinline__ void stage_swz(const unsigned short* __restrict__ src,
                                          unsigned short* dst) {
    for (int idx = threadIdx.x; idx < 1024; idx += 256) {
        const int c = idx >> 6, ln = idx & 63;
        *(uint4*)(dst + (size_t)idx * 8) =
            *(const uint4*)(src + (size_t)(ln & 15) * 512 + (ln >> 4) * 8 + c * 32);
    }
}

// ---------- micro-GEMMs: A-frags via coherent loads, W from swizzled LDS ----------
__device__ __forceinline__ void mm3_s(const unsigned short* __restrict__ A, int m0,
                                      const unsigned short* Wl, int lane,
                                      f32x4& a0, f32x4& a1, f32x4& a2) {
    const unsigned short* ab = A + (size_t)(m0 + (lane & 15)) * 512 + (lane >> 4) * 8;
#pragma unroll
    for (int c = 0; c < 16; ++c) {
        s16x8 a = ldA_sc(ab + c * 32);
        a0 = MFMA_B16(a, WF(Wl, 0, c, lane), a0);
        a1 = MFMA_B16(a, WF(Wl, 1, c, lane), a1);
        a2 = MFMA_B16(a, WF(Wl, 2, c, lane), a2);
    }
}
__device__ __forceinline__ void mm6_s(const unsigned short* __restrict__ A0,
                                      const unsigned short* __restrict__ A1, int m0,
                                      const unsigned short* Wl, int lane,
                                      f32x4& aR, f32x4& aZ, f32x4& aIN, f32x4& aHN) {
    const unsigned short* a0 = A0 + (size_t)(m0 + (lane & 15)) * 512 + (lane >> 4) * 8;
    const unsigned short* a1 = A1 + (size_t)(m0 + (lane & 15)) * 512 + (lane >> 4) * 8;
#pragma unroll
    for (int c = 0; c < 16; ++c) {
        s16x8 x0 = ldA_sc(a0 + c * 32);
        s16x8 x1 = ldA_sc(a1 + c * 32);
        aR  = MFMA_B16(x0, WF(Wl, 0, c, lane), aR);
        aZ  = MFMA_B16(x0, WF(Wl, 1, c, lane), aZ);
        aIN = MFMA_B16(x0, WF(Wl, 2, c, lane), aIN);
        aR  = MFMA_B16(x1, WF(Wl, 3, c, lane), aR);
        aZ  = MFMA_B16(x1, WF(Wl, 4, c, lane), aZ);
        aHN = MFMA_B16(x1, WF(Wl, 5, c, lane), aHN);
    }
}

// ---------- prep: bf16 conversions (incl. x transposed to (t,b,f)), zeroing ----------
__global__ void prep_kernel(const float* __restrict__ x, const float* __restrict__ Wih_v,
                            const float* __restrict__ Whh_v, const float* __restrict__ Whh_c,
                            const float* __restrict__ Wih_c, const float* __restrict__ Wout,
                            unsigned short* __restrict__ xB, unsigned short* __restrict__ WihB,
                            unsigned short* __restrict__ WhhvB, unsigned short* __restrict__ WhhcB,
                            unsigned short* __restrict__ WchhB, unsigned short* __restrict__ WoutB,
                            unsigned short* __restrict__ zeroB, int* __restrict__ ctrs,
                            float* __restrict__ out) {
    const int n = gridDim.x * blockDim.x;
    const int id0 = blockIdx.x * blockDim.x + threadIdx.x;
    // x (b,t,f) fp32 -> xB (t*64+b, f) bf16, vectorized by 4
    for (int i = id0; i < 5242880; i += n) {
        const int e = i * 4;
        const int f = e & 4095, bt = e >> 12;      // bt = b*80+t
        const int b = bt / 80, t = bt - b * 80;
        float4 v = *(const float4*)(x + (size_t)e);
        u16x4 s = {f2b(v.x), f2b(v.y), f2b(v.z), f2b(v.w)};
        *(u16x4*)(xB + (size_t)(t * 64 + b) * 4096 + f) = s;
    }
    for (int i = id0; i < 1572864; i += n) {
        float4 v = *(const float4*)(Wih_v + (size_t)i * 4);
        u16x4 s = {f2b(v.x), f2b(v.y), f2b(v.z), f2b(v.w)};
        *(u16x4*)(WihB + (size_t)i * 4) = s;
    }
    for (int i = id0; i < 786432; i += n) {
        WhhvB[i] = f2b(Whh_v[i]);
        WhhcB[i] = f2b(Whh_c[i]);
        WchhB[i] = f2b(Wih_c[(size_t)(i >> 9) * 6512 + (i & 511)]);  // Wih_c[:, :512]
    }
    for (int i = id0; i < 3072000; i += n) WoutB[i] = f2b(Wout[i]);
    for (int i = id0; i < 384000; i += n)  // probs[:,0,:] = 0 except probs[0,0,1]=1
        out[(size_t)(i / 6000) * 192000 + (i % 6000)] = (i == 1) ? 1.f : 0.f;
    for (int i = id0; i < 32768; i += n) zeroB[i] = 0;
    if (id0 < 1024) ctrs[id0] = 0;
}

// ---------- GEMM1 (bf16 in): gi[t*64+b, g] = xB[t*64+b,:] . WihB[g,:] + bih[g] ----------
__global__ __launch_bounds__(256) void gemm1_kernel(const unsigned short* __restrict__ xB,
                                                    const unsigned short* __restrict__ WihB,
                                                    const float* __restrict__ bih,
                                                    float* __restrict__ gi) {
    __shared__ unsigned short As[128 * 40];
    __shared__ unsigned short Bs[128 * 40];
    const int bm = blockIdx.x % 40;
    const int bn = blockIdx.x / 40;
    const int m0 = bm * 128, n0 = bn * 128;
    const int tid = threadIdx.x;
    const int lane = tid & 63;
    const int wave = tid >> 6;
    const int wm = (wave >> 1) * 64, wn = (wave & 1) * 64;
    const int quad = lane >> 4, l15 = lane & 15;

    const f32x4 z4 = {0.f, 0.f, 0.f, 0.f};
    f32x4 acc[4][4];
#pragma unroll
    for (int i = 0; i < 4; ++i)
#pragma unroll
        for (int j = 0; j < 4; ++j) acc[i][j] = z4;

    const int sr = tid >> 1;                 // row 0..127
    const int sc0 = (tid & 1) * 16;          // col group {0,16}

    for (int k0 = 0; k0 < 4096; k0 += 32) {
        __syncthreads();
#pragma unroll
        for (int p = 0; p < 2; ++p) {
            const int c8 = sc0 + p * 8;
            *(s16x8*)&As[sr * 40 + c8] =
                *(const s16x8*)(xB + (size_t)(m0 + sr) * 4096 + k0 + c8);
            *(s16x8*)&Bs[sr * 40 + c8] =
                *(const s16x8*)(WihB + (size_t)(n0 + sr) * 4096 + k0 + c8);
        }
        __syncthreads();
        s16x8 af[4], bfr[4];
#pragma unroll
        for (int i = 0; i < 4; ++i) af[i] = *(const s16x8*)&As[(wm + i * 16 + l15) * 40 + quad * 8];
#pragma unroll
        for (int j = 0; j < 4; ++j) bfr[j] = *(const s16x8*)&Bs[(wn + j * 16 + l15) * 40 + quad * 8];
#pragma unroll
        for (int i = 0; i < 4; ++i)
#pragma unroll
            for (int j = 0; j < 4; ++j) acc[i][j] = MFMA_B16(af[i], bfr[j], acc[i][j]);
    }
#pragma unroll
    for (int i = 0; i < 4; ++i)
#pragma unroll
        for (int j = 0; j < 4; ++j)
#pragma unroll
            for (int r = 0; r < 4; ++r) {
                const int m = m0 + wm + i * 16 + quad * 4 + r;
                const int nn = n0 + wn + j * 16 + l15;
                gi[(size_t)m * 1536 + nn] = acc[i][j][r] + bih[nn];
            }
}

// ---------- persistent pipeline kernel ----------
// blocks 0..31   group_v: enc_v chain + decoder h_v2 chain + loss
// blocks 32..63  group_c: enc_c chain + decoder h_c
// blocks 64..188 group_o: WcwT transpose (encoder slack) + logits
struct SeqParams {
    const float* bih_v; const float* bhh_v;
    const float* bih_c; const float* bhh_c;
    const float* bout;  const int* y;
    const float* gi;    const float* Wc;  float* out;
    const unsigned short* WhhvB; const unsigned short* WhhcB; const unsigned short* WchhB;
    const unsigned short* WoutB; unsigned short* WcwTB;
    unsigned short* eo;    // 80 x (64x512) bf16
    unsigned short* hv2B;  // 32 x (64x512) bf16  (hv2B[0] = bf16(hidden_video))
    unsigned short* hcdB;  // 31 x (64x512) bf16
    unsigned short* ecb0; unsigned short* ecb1; unsigned short* zeroB;
    float* hcf; float* lossP; int* ctr;
};
// counters (each at ctr + k*64): 0 eo-progress, 1 ecb/enc_c-progress, 2 hv2-progress,
// 3 hcd-progress, 4 logits-done(500), 5 loss-partials(64), 6 transpose-done(125)
#define CTR(k) (p.ctr + (k) * 64)

__global__ __launch_bounds__(256, 1) void seq_kernel(SeqParams p) {
    __shared__ unsigned short Wlds[49152];  // 96 KiB
    const int blk = blockIdx.x;
    const int lane = threadIdx.x & 63;
    const int wave = threadIdx.x >> 6;
    const int quad = lane >> 4, l15 = lane & 15;
    const f32x4 z4 = {0.f, 0.f, 0.f, 0.f};

    if (blk < 32) {
        // ================= group_v =================
        const int j0 = blk * 16;
        const int j = j0 + l15;
        const int m0 = wave * 16;
        const int b_ = m0 + quad * 4;
#pragma unroll
        for (int g = 0; g < 3; ++g)
            stage_swz(p.WhhvB + (size_t)(g * 512 + j0) * 512, Wlds + g * WTILE);
        __syncthreads();
        const float bhr = p.bhh_v[j], bhz = p.bhh_v[512 + j], bhn = p.bhh_v[1024 + j];
        float hp[4] = {0.f, 0.f, 0.f, 0.f};

        for (int t = 0; t < 80; ++t) {
            float gr[4], gz[4], gn[4];  // prefetch gi[t] (off-chain, plain cached loads)
            const float* gt = p.gi + (size_t)t * 98304;
#pragma unroll
            for (int r = 0; r < 4; ++r) {
                const float* gb = gt + (size_t)(b_ + r) * 1536;
                gr[r] = gb[j]; gz[r] = gb[512 + j]; gn[r] = gb[1024 + j];
            }
            f32x4 aR = z4, aZ = z4, aN = z4;
            if (t > 0) {
                wave_wait(CTR(0), 128 * t);
                mm3_s(p.eo + (size_t)(t - 1) * 32768, m0, Wlds, lane, aR, aZ, aN);
            }
            unsigned short* eoW = p.eo + (size_t)t * 32768;
#pragma unroll
            for (int r = 0; r < 4; ++r) {
                float rg = sigm(gr[r] + aR[r] + bhr);
                float zg = sigm(gz[r] + aZ[r] + bhz);
                float ng = tanh_f(gn[r] + rg * (aN[r] + bhn));
                float hn = (1.f - zg) * ng + zg * hp[r];
                hp[r] = hn;
                stg_b16_sc(eoW + (size_t)(b_ + r) * 512 + j, f2b(hn));
            }
            wave_signal(CTR(0));
        }

        // ----- decoder h_v2 chain -----
        wave_wait(CTR(1), 128 * 80);  // hcf + hv2B[0] ready
        const float bir = p.bih_v[j], biz = p.bih_v[512 + j], bin_ = p.bih_v[1024 + j];
        for (int s = 0; s <= 30; ++s) {
            if (s > 0) wave_wait(CTR(2), 128 * s);
            f32x4 aR = z4, aZ = z4, aN = z4;
            mm3_s(p.hv2B + (size_t)s * 32768, m0, Wlds, lane, aR, aZ, aN);
            unsigned short* hw = p.hv2B + (size_t)(s + 1) * 32768;
#pragma unroll
            for (int r = 0; r < 4; ++r) {
                float hpv = (s == 0) ? ldg_f32_sc(p.hcf + (size_t)(b_ + r) * 512 + j) : hp[r];
                float rg = sigm(bir + aR[r] + bhr);
                float zg = sigm(biz + aZ[r] + bhz);
                float ng = tanh_f(bin_ + rg * (aN[r] + bhn));
                float hn = (1.f - zg) * ng + zg * hpv;
                hp[r] = hn;
                stg_b16_sc(hw + (size_t)(b_ + r) * 512 + j, f2b(hn));
            }
            wave_signal(CTR(2));
        }

        // ----- loss (blocks 0..15: row b = blk*4+wave) -----
        if (blk < 16) {
            const int b = (blk << 2) | wave;
            wave_wait(CTR(4), 500);
            const float* lg = p.out + (size_t)b * 192000 + 186000;
            float m = -1e30f, sum = 0.f;
            for (int i = lane; i < 3000; i += 64) {
                union { unsigned long long u; float f[2]; } pr;
                pr.u = ldg_u64_sc(lg + 2 * i);
#pragma unroll
                for (int e = 0; e < 2; ++e) {
                    float v = pr.f[e];
                    float nm = fmaxf(m, v);
                    sum = sum * __expf(m - nm) + __expf(v - nm);
                    m = nm;
                }
            }
#pragma unroll
            for (int off = 32; off > 0; off >>= 1) {
                float m2 = __shfl_down(m, off);
                float s2 = __shfl_down(sum, off);
                float nm = fmaxf(m, m2);
                sum = sum * __expf(m - nm) + s2 * __expf(m2 - nm);
                m = nm;
            }
            if (lane == 0) {
                int yv = p.y[31 * 64 + b];
                float lgy = ldg_f32_sc(lg + yv);
                stg_b32_sc(p.lossP + b, (m + __logf(sum)) - lgy);
            }
            wave_signal(CTR(5));
            if (blk == 0 && wave == 0) {
                wave_wait(CTR(5), 64);
                float v = ldg_f32_sc(p.lossP + lane);
#pragma unroll
                for (int off = 32; off > 0; off >>= 1) v += __shfl_down(v, off);
                if (lane == 0) p.out[12288000] = v * (1.f / 64.f);
            }
        }
    } else if (blk < 64) {
        // ================= group_c =================
        const int j0 = (blk - 32) * 16;
        const int j = j0 + l15;
        const int m0 = wave * 16;
        const int b_ = m0 + quad * 4;
#pragma unroll
        for (int g = 0; g < 3; ++g) {
            stage_swz(p.WchhB + (size_t)(g * 512 + j0) * 512, Wlds + g * WTILE);
            stage_swz(p.WhhcB + (size_t)(g * 512 + j0) * 512, Wlds + (3 + g) * WTILE);
        }
        __syncthreads();
        const float bcr = p.bih_c[j] + p.bhh_c[j];
        const float bcz = p.bih_c[512 + j] + p.bhh_c[512 + j];
        const float bin_ = p.bih_c[1024 + j];
        const float bhn = p.bhh_c[1024 + j];
        float hp[4] = {0.f, 0.f, 0.f, 0.f};

        for (int t = 0; t < 80; ++t) {
            wave_wait(CTR(0), 128 * (t + 1));           // eo[t] ready
            if (t > 0) wave_wait(CTR(1), 128 * t);      // ecb[t-1] ready
            const unsigned short* A1 = (t == 0) ? p.zeroB : ((t & 1) ? p.ecb0 : p.ecb1);
            unsigned short* ew = (t & 1) ? p.ecb1 : p.ecb0;
            f32x4 aR = z4, aZ = z4, aIN = z4, aHN = z4;
            mm6_s(p.eo + (size_t)t * 32768, A1, m0, Wlds, lane, aR, aZ, aIN, aHN);
#pragma unroll
            for (int r = 0; r < 4; ++r) {
                float rg = sigm(aR[r] + bcr);
                float zg = sigm(aZ[r] + bcz);
                float ng = tanh_f(aIN[r] + bin_ + rg * (aHN[r] + bhn));
                float hn = (1.f - zg) * ng + zg * hp[r];
                hp[r] = hn;
                unsigned short hb = f2b(hn);
                stg_b16_sc(ew + (size_t)(b_ + r) * 512 + j, hb);
                if (t == 79) {
                    stg_b16_sc(p.hv2B + (size_t)(b_ + r) * 512 + j, hb);
                    stg_b32_sc(p.hcf + (size_t)(b_ + r) * 512 + j, hn);
                }
            }
            wave_signal(CTR(1));
        }

        // ----- decoder h_c (no inter-step chain) -----
        wave_wait(CTR(6), 125);  // WcwT ready (atomic-written by group_o)
        for (int s = 0; s <= 30; ++s) {
            wave_wait(CTR(2), 128 * (s + 1));
            const unsigned short* hv = p.hv2B + (size_t)(s + 1) * 32768;
            f32x4 aR = z4, aZ = z4, aIN = z4, aHN = z4;
            mm6_s(hv, hv, m0, Wlds, lane, aR, aZ, aIN, aHN);
            unsigned short* hc = p.hcdB + (size_t)s * 32768;
#pragma unroll
            for (int r = 0; r < 4; ++r) {
                const int yv = p.y[s * 64 + (b_ + r)];
                const unsigned short* em = p.WcwTB + (size_t)yv * 1536;
                float rg = sigm(aR[r] + ldg_b16_sc(em + j) + bcr);
                float zg = sigm(aZ[r] + ldg_b16_sc(em + 512 + j) + bcz);
                float ng = tanh_f(aIN[r] + ldg_b16_sc(em + 1024 + j) + bin_ +
                                  rg * (aHN[r] + bhn));
                float hpv = ldg_b16_sc(hv + (size_t)(b_ + r) * 512 + j);
                stg_b16_sc(hc + (size_t)(b_ + r) * 512 + j, f2b((1.f - zg) * ng + zg * hpv));
            }
            wave_signal(CTR(3));
        }
    } else {
        // ================= group_o =================
        const int bo = blk - 64;          // 0..124
        const int w0 = bo * 48;           // 48 Wout cols each
#pragma unroll
        for (int tl = 0; tl < 3; ++tl)
            stage_swz(p.WoutB + (size_t)(w0 + tl * 16) * 512, Wlds + tl * WTILE);
        __syncthreads();

        // --- WcwT transpose during encoder slack: block bo handles cols bo*64..+63 ---
        if (bo < 94) {
            float* tile = (float*)(Wlds + 24576);  // 64x65 fp32 scratch after Wout tiles
            const int w0t = bo * 64;
            const int tx = threadIdx.x & 63, ty = threadIdx.x >> 6;
            for (int gt = 0; gt < 24; ++gt) {
                const int g0 = gt * 64;
                __syncthreads();
                for (int r = ty; r < 64; r += 4) {
                    int w = w0t + tx;
                    tile[r * 65 + tx] = (w < 6000) ? p.Wc[(size_t)(g0 + r) * 6512 + 512 + w] : 0.f;
                }
                __syncthreads();
                for (int r = ty; r < 64; r += 4) {
                    int w = w0t + r;
                    if (w < 6000)
                        stg_b16_sc(p.WcwTB + (size_t)w * 1536 + g0 + tx, f2b(tile[tx * 65 + r]));
                }
            }
        }
        __syncthreads();  // implies per-wave vmcnt drain before barrier
        if (threadIdx.x == 0)
            __hip_atomic_fetch_add(CTR(6), 1, __ATOMIC_RELAXED, __HIP_MEMORY_SCOPE_AGENT);

        // --- logits ---
        const int m0 = wave * 16;
        const int b_ = m0 + quad * 4;
        float bo_[3];
#pragma unroll
        for (int tl = 0; tl < 3; ++tl) bo_[tl] = p.bout[w0 + tl * 16 + l15];

        for (int s = 0; s <= 30; ++s) {
            wave_wait(CTR(3), 128 * (s + 1));
            const unsigned short* ab =
                p.hcdB + (size_t)s * 32768 + (size_t)(m0 + l15) * 512 + quad * 8;
            s16x8 af[16];
#pragma unroll
            for (int c = 0; c < 16; ++c) af[c] = ldA_sc(ab + c * 32);
#pragma unroll
            for (int tl = 0; tl < 3; ++tl) {
                f32x4 acc = z4;
#pragma unroll
                for (int c = 0; c < 16; ++c) acc = MFMA_B16(af[c], WF(Wlds, tl, c, lane), acc);
#pragma unroll
                for (int r = 0; r < 4; ++r)
                    stg_b32_sc(p.out + (size_t)(b_ + r) * 192000 + (size_t)(s + 1) * 6000 +
                                   w0 + tl * 16 + l15,
                               acc[r] + bo_[tl]);
            }
        }
        wave_signal(CTR(4));
    }
}

// ---------- host ----------
extern "C" void kernel_launch(void* const* d_in, const int* in_sizes, int n_in,
                              void* d_out, int out_size, void* d_ws, size_t ws_size,
                              hipStream_t stream) {
    const float* x     = (const float*)d_in[0];
    const int*   y     = (const int*)d_in[1];
    const float* Wih_v = (const float*)d_in[2];
    const float* Whh_v = (const float*)d_in[3];
    const float* bih_v = (const float*)d_in[4];
    const float* bhh_v = (const float*)d_in[5];
    const float* Wih_c = (const float*)d_in[6];
    const float* Whh_c = (const float*)d_in[7];
    const float* bih_c = (const float*)d_in[8];
    const float* bhh_c = (const float*)d_in[9];
    const float* Wout  = (const float*)d_in[10];
    const float* bout  = (const float*)d_in[11];
    float* out = (float*)d_out;

    char* w = (char*)d_ws;
    size_t o = 0;
    auto alloc = [&](size_t bytes) -> void* {
        void* p = (void*)(w + o);
        o += (bytes + 255) & ~(size_t)255;
        return p;
    };
    float*          gi    = (float*)alloc(7864320ull * 4);
    unsigned short* xB    = (unsigned short*)alloc(20971520ull * 2);
    unsigned short* WihB  = (unsigned short*)alloc(6291456ull * 2);
    unsigned short* WhhvB = (unsigned short*)alloc(786432ull * 2);
    unsigned short* WhhcB = (unsigned short*)alloc(786432ull * 2);
    unsigned short* WchhB = (unsigned short*)alloc(786432ull * 2);
    unsigned short* WoutB = (unsigned short*)alloc(3072000ull * 2);
    unsigned short* WcwTB = (unsigned short*)alloc(9216000ull * 2);
    unsigned short* eo    = (unsigned short*)alloc(80ull * 32768 * 2);
    unsigned short* hv2B  = (unsigned short*)alloc(32ull * 32768 * 2);
    unsigned short* hcdB  = (unsigned short*)alloc(31ull * 32768 * 2);
    unsigned short* ecb0  = (unsigned short*)alloc(32768ull * 2);
    unsigned short* ecb1  = (unsigned short*)alloc(32768ull * 2);
    unsigned short* zeroB = (unsigned short*)alloc(32768ull * 2);
    float*          hcf   = (float*)alloc(32768ull * 4);
    float*          lossP = (float*)alloc(64ull * 4);
    int*            ctrs  = (int*)alloc(1024ull * 4);
    if (o > ws_size) return;

    prep_kernel<<<512, 256, 0, stream>>>(x, Wih_v, Whh_v, Whh_c, Wih_c, Wout, xB, WihB,
                                         WhhvB, WhhcB, WchhB, WoutB, zeroB, ctrs, out);
    gemm1_kernel<<<480, 256, 0, stream>>>(xB, WihB, bih_v, gi);

    SeqParams p;
    p.bih_v = bih_v; p.bhh_v = bhh_v; p.bih_c = bih_c; p.bhh_c = bhh_c;
    p.bout = bout; p.y = y; p.gi = gi; p.Wc = Wih_c; p.out = out;
    p.WhhvB = WhhvB; p.WhhcB = WhhcB; p.WchhB = WchhB; p.WoutB = WoutB; p.WcwTB = WcwTB;
    p.eo = eo; p.hv2B = hv2B; p.hcdB = hcdB;
    p.ecb0 = ecb0; p.ecb1 = ecb1; p.zeroB = zeroB;
    p.hcf = hcf; p.lossP = lossP; p.ctr = ctrs;
    void* args[] = {&p};
    hipLaunchCooperativeKernel((void*)seq_kernel, dim3(189), dim3(256), args, 0, stream);
}

// Round 5
// 1431.204 us; speedup vs baseline: 7.8121x; 1.2921x over previous
//
#include <hip/hip_runtime.h>

// ---------- types / helpers ----------
typedef short s16x8 __attribute__((ext_vector_type(8)));   // 8 bf16 (4 VGPRs) MFMA A/B frag
typedef float f32x4 __attribute__((ext_vector_type(4)));   // MFMA C/D frag
typedef unsigned short u16x4 __attribute__((ext_vector_type(4)));

#define MFMA_B16(a, b, c) __builtin_amdgcn_mfma_f32_16x16x32_bf16((a), (b), (c), 0, 0, 0)

__device__ __forceinline__ unsigned short f2b(float f) {   // fp32 -> bf16 RNE
    unsigned u = __builtin_bit_cast(unsigned, f);
    u = (u + 0x7fffu + ((u >> 16) & 1u)) >> 16;
    return (unsigned short)u;
}
__device__ __forceinline__ float b2f(unsigned short h) {
    unsigned u = ((unsigned)h) << 16;
    return __builtin_bit_cast(float, u);
}
__device__ __forceinline__ float sigm(float x) { return 1.f / (1.f + __expf(-x)); }
__device__ __forceinline__ float tanh_f(float x) {
    float t = __expf(-2.f * fabsf(x));
    float r = (1.f - t) / (1.f + t);
    return copysignf(r, x);
}

// ---------- coherent-bypass data ops (sc1; no cache-wide maintenance) ----------
__device__ __forceinline__ void stg_b16_sc(unsigned short* p, unsigned short v) {
    unsigned v32 = v;
    asm volatile("global_store_short %0, %1, off sc1" :: "v"(p), "v"(v32) : "memory");
}
__device__ __forceinline__ void stg_b32_sc(float* p, float v) {
    asm volatile("global_store_dword %0, %1, off sc1" :: "v"(p), "v"(v) : "memory");
}
__device__ __forceinline__ unsigned long long ldg_u64_sc(const void* p) {
    return __hip_atomic_load((unsigned long long*)p, __ATOMIC_RELAXED, __HIP_MEMORY_SCOPE_AGENT);
}
__device__ __forceinline__ float ldg_b16_sc(const unsigned short* p) {
    unsigned short v = __hip_atomic_load((unsigned short*)p, __ATOMIC_RELAXED, __HIP_MEMORY_SCOPE_AGENT);
    return b2f(v);
}
__device__ __forceinline__ float ldg_f32_sc(const float* p) {
    return __hip_atomic_load((float*)p, __ATOMIC_RELAXED, __HIP_MEMORY_SCOPE_AGENT);
}
__device__ __forceinline__ s16x8 ldA_sc(const unsigned short* p) {
    union { unsigned long long u[2]; s16x8 v; } r;
    r.u[0] = ldg_u64_sc(p);
    r.u[1] = ldg_u64_sc((const unsigned long long*)p + 1);
    return r.v;
}

// ---------- flag protocol: one 64B-separated dword flag per producer block ----------
// publish: drain data stores, block barrier, single relaxed store of step number.
__device__ __forceinline__ void block_publish(int* flag, int v) {
    asm volatile("s_waitcnt vmcnt(0)" ::: "memory");
    __syncthreads();
    if (threadIdx.x == 0)
        __hip_atomic_store(flag, v, __ATOMIC_RELAXED, __HIP_MEMORY_SCOPE_AGENT);
}
// wait: lanes 0..31 poll f1[lane], lanes 32..63 poll f2[lane-32]; one load/poll/wave.
template <int SLP>
__device__ __forceinline__ void flags_wait2(const int* f1, int t1, const int* f2, int t2) {
    const int lane = threadIdx.x & 63;
    const int* ptr = (lane < 32) ? (f1 + lane * 16) : (f2 + (lane - 32) * 16);
    const int tgt = (lane < 32) ? t1 : t2;
    for (;;) {
        int v = __hip_atomic_load((int*)ptr, __ATOMIC_RELAXED, __HIP_MEMORY_SCOPE_AGENT);
        if (__all(v >= tgt)) break;
        __builtin_amdgcn_s_sleep(SLP);
    }
}
template <int SLP>
__device__ __forceinline__ void flags_wait(const int* f, int t) {
    flags_wait2<SLP>(f, t, f, t);
}
template <int SLP>
__device__ __forceinline__ void scalar_wait(int* c, int target) {
    while (__hip_atomic_load(c, __ATOMIC_RELAXED, __HIP_MEMORY_SCOPE_AGENT) < target)
        __builtin_amdgcn_s_sleep(SLP);
}
__device__ __forceinline__ void wave_add(int* c) {   // per-wave count (after drain)
    asm volatile("s_waitcnt vmcnt(0)" ::: "memory");
    if ((threadIdx.x & 63) == 0)
        __hip_atomic_fetch_add(c, 1, __ATOMIC_RELAXED, __HIP_MEMORY_SCOPE_AGENT);
}

// ---------- swizzled LDS weight tiles (16x512 bf16 in B-fragment order; conflict-free) ----------
#define WTILE 8192  // shorts per tile
#define WF(Wl, t, c, lane) (*(const s16x8*)((Wl) + (((t) * 16 + (c)) * 64 + (lane)) * 8))

__device__ __forceinline__ void stage_swz(const unsigned short* __restrict__ src,
                                          unsigned short* dst) {
    for (int idx = threadIdx.x; idx < 1024; idx += 256) {
        const int ln = idx & 63;
        *(uint4*)(dst + (size_t)idx * 8) =
            *(const uint4*)(src + (size_t)(ln & 15) * 512 + (ln >> 4) * 8 + ((idx >> 6)) * 32);
    }
}

// ---------- micro-GEMMs: A-frags via coherent loads, W from swizzled LDS ----------
__device__ __forceinline__ void mm3_s(const unsigned short* __restrict__ A, int m0,
                                      const unsigned short* Wl, int lane,
                                      f32x4& a0, f32x4& a1, f32x4& a2) {
    const unsigned short* ab = A + (size_t)(m0 + (lane & 15)) * 512 + (lane >> 4) * 8;
#pragma unroll
    for (int c = 0; c < 16; ++c) {
        s16x8 a = ldA_sc(ab + c * 32);
        a0 = MFMA_B16(a, WF(Wl, 0, c, lane), a0);
        a1 = MFMA_B16(a, WF(Wl, 1, c, lane), a1);
        a2 = MFMA_B16(a, WF(Wl, 2, c, lane), a2);
    }
}
__device__ __forceinline__ void mm6_s(const unsigned short* __restrict__ A0,
                                      const unsigned short* __restrict__ A1, int m0,
                                      const unsigned short* Wl, int lane,
                                      f32x4& aR, f32x4& aZ, f32x4& aIN, f32x4& aHN) {
    const unsigned short* a0 = A0 + (size_t)(m0 + (lane & 15)) * 512 + (lane >> 4) * 8;
    const unsigned short* a1 = A1 + (size_t)(m0 + (lane & 15)) * 512 + (lane >> 4) * 8;
#pragma unroll
    for (int c = 0; c < 16; ++c) {
        s16x8 x0 = ldA_sc(a0 + c * 32);
        s16x8 x1 = ldA_sc(a1 + c * 32);
        aR  = MFMA_B16(x0, WF(Wl, 0, c, lane), aR);
        aZ  = MFMA_B16(x0, WF(Wl, 1, c, lane), aZ);
        aIN = MFMA_B16(x0, WF(Wl, 2, c, lane), aIN);
        aR  = MFMA_B16(x1, WF(Wl, 3, c, lane), aR);
        aZ  = MFMA_B16(x1, WF(Wl, 4, c, lane), aZ);
        aHN = MFMA_B16(x1, WF(Wl, 5, c, lane), aHN);
    }
}

// ---------- prep ----------
__global__ void prep_kernel(const float* __restrict__ x, const float* __restrict__ Wih_v,
                            const float* __restrict__ Whh_v, const float* __restrict__ Whh_c,
                            const float* __restrict__ Wih_c, const float* __restrict__ Wout,
                            unsigned short* __restrict__ xB, unsigned short* __restrict__ WihB,
                            unsigned short* __restrict__ WhhvB, unsigned short* __restrict__ WhhcB,
                            unsigned short* __restrict__ WchhB, unsigned short* __restrict__ WoutB,
                            unsigned short* __restrict__ zeroB, int* __restrict__ ctrs,
                            float* __restrict__ out) {
    const int n = gridDim.x * blockDim.x;
    const int id0 = blockIdx.x * blockDim.x + threadIdx.x;
    for (int i = id0; i < 5242880; i += n) {   // x (b,t,f) fp32 -> xB (t*64+b, f) bf16
        const int e = i * 4;
        const int f = e & 4095, bt = e >> 12;  // bt = b*80+t
        const int b = bt / 80, t = bt - b * 80;
        float4 v = *(const float4*)(x + (size_t)e);
        u16x4 s = {f2b(v.x), f2b(v.y), f2b(v.z), f2b(v.w)};
        *(u16x4*)(xB + (size_t)(t * 64 + b) * 4096 + f) = s;
    }
    for (int i = id0; i < 1572864; i += n) {
        float4 v = *(const float4*)(Wih_v + (size_t)i * 4);
        u16x4 s = {f2b(v.x), f2b(v.y), f2b(v.z), f2b(v.w)};
        *(u16x4*)(WihB + (size_t)i * 4) = s;
    }
    for (int i = id0; i < 786432; i += n) {
        WhhvB[i] = f2b(Whh_v[i]);
        WhhcB[i] = f2b(Whh_c[i]);
        WchhB[i] = f2b(Wih_c[(size_t)(i >> 9) * 6512 + (i & 511)]);  // Wih_c[:, :512]
    }
    for (int i = id0; i < 3072000; i += n) WoutB[i] = f2b(Wout[i]);
    for (int i = id0; i < 384000; i += n)  // probs[:,0,:] = 0 except probs[0,0,1]=1
        out[(size_t)(i / 6000) * 192000 + (i % 6000)] = (i == 1) ? 1.f : 0.f;
    for (int i = id0; i < 32768; i += n) zeroB[i] = 0;
    for (int i = id0; i < 4096; i += n) ctrs[i] = 0;
}

// ---------- GEMM1 (bf16 in): gi[t*64+b, g] = xB[t*64+b,:] . WihB[g,:] + bih[g] ----------
__global__ __launch_bounds__(256) void gemm1_kernel(const unsigned short* __restrict__ xB,
                                                    const unsigned short* __restrict__ WihB,
                                                    const float* __restrict__ bih,
                                                    float* __restrict__ gi) {
    __shared__ unsigned short As[128 * 40];
    __shared__ unsigned short Bs[128 * 40];
    const int bm = blockIdx.x % 40;
    const int bn = blockIdx.x / 40;
    const int m0 = bm * 128, n0 = bn * 128;
    const int tid = threadIdx.x;
    const int lane = tid & 63;
    const int wave = tid >> 6;
    const int wm = (wave >> 1) * 64, wn = (wave & 1) * 64;
    const int quad = lane >> 4, l15 = lane & 15;

    const f32x4 z4 = {0.f, 0.f, 0.f, 0.f};
    f32x4 acc[4][4];
#pragma unroll
    for (int i = 0; i < 4; ++i)
#pragma unroll
        for (int j = 0; j < 4; ++j) acc[i][j] = z4;

    const int sr = tid >> 1;
    const int sc0 = (tid & 1) * 16;

    for (int k0 = 0; k0 < 4096; k0 += 32) {
        __syncthreads();
#pragma unroll
        for (int p = 0; p < 2; ++p) {
            const int c8 = sc0 + p * 8;
            *(s16x8*)&As[sr * 40 + c8] =
                *(const s16x8*)(xB + (size_t)(m0 + sr) * 4096 + k0 + c8);
            *(s16x8*)&Bs[sr * 40 + c8] =
                *(const s16x8*)(WihB + (size_t)(n0 + sr) * 4096 + k0 + c8);
        }
        __syncthreads();
        s16x8 af[4], bfr[4];
#pragma unroll
        for (int i = 0; i < 4; ++i) af[i] = *(const s16x8*)&As[(wm + i * 16 + l15) * 40 + quad * 8];
#pragma unroll
        for (int j = 0; j < 4; ++j) bfr[j] = *(const s16x8*)&Bs[(wn + j * 16 + l15) * 40 + quad * 8];
#pragma unroll
        for (int i = 0; i < 4; ++i)
#pragma unroll
            for (int j = 0; j < 4; ++j) acc[i][j] = MFMA_B16(af[i], bfr[j], acc[i][j]);
    }
#pragma unroll
    for (int i = 0; i < 4; ++i)
#pragma unroll
        for (int j = 0; j < 4; ++j)
#pragma unroll
            for (int r = 0; r < 4; ++r) {
                const int m = m0 + wm + i * 16 + quad * 4 + r;
                const int nn = n0 + wn + j * 16 + l15;
                gi[(size_t)m * 1536 + nn] = acc[i][j][r] + bih[nn];
            }
}

// ---------- persistent pipeline kernel ----------
// blocks 0..31   group_v: enc_v chain + decoder h_v2 chain + loss
// blocks 32..63  group_c: enc_c chain + decoder h_c
// blocks 64..188 group_o: WcwT transpose (encoder slack) + logits
struct SeqParams {
    const float* bih_v; const float* bhh_v;
    const float* bih_c; const float* bhh_c;
    const float* bout;  const int* y;
    const float* gi;    const float* Wc;  float* out;
    const unsigned short* WhhvB; const unsigned short* WhhcB; const unsigned short* WchhB;
    const unsigned short* WoutB; unsigned short* WcwTB;
    unsigned short* eo;    // 80 x (64x512) bf16
    unsigned short* hv2B;  // 32 x (64x512) bf16
    float*          hv2F;  // 32 x (64x512) fp32 (decoder carry in fp32)
    unsigned short* hcdB;  // 31 x (64x512) bf16
    unsigned short* ecb0; unsigned short* ecb1; unsigned short* zeroB;
    float* hcf; float* lossP; int* ctr;
};
// flag arrays (stride 16 ints = 64B): F_EO=0, F_EC=512, F_HV=1024, F_HC=1536
// scalars: S_TR=+2048, S_LOG=+2064, S_LP=+2080
#define F_EO (p.ctr)
#define F_EC (p.ctr + 512)
#define F_HV (p.ctr + 1024)
#define F_HC (p.ctr + 1536)
#define S_TR (p.ctr + 2048)
#define S_LOG (p.ctr + 2064)
#define S_LP (p.ctr + 2080)

__global__ __launch_bounds__(256, 1) void seq_kernel(SeqParams p) {
    __shared__ unsigned short Wlds[49152];  // 96 KiB
    const int blk = blockIdx.x;
    const int lane = threadIdx.x & 63;
    const int wave = threadIdx.x >> 6;
    const int quad = lane >> 4, l15 = lane & 15;
    const f32x4 z4 = {0.f, 0.f, 0.f, 0.f};

    if (blk < 32) {
        // ================= group_v =================
        const int j0 = blk * 16;
        const int j = j0 + l15;
        const int m0 = wave * 16;
        const int b_ = m0 + quad * 4;
#pragma unroll
        for (int g = 0; g < 3; ++g)
            stage_swz(p.WhhvB + (size_t)(g * 512 + j0) * 512, Wlds + g * WTILE);
        __syncthreads();
        const float bhr = p.bhh_v[j], bhz = p.bhh_v[512 + j], bhn = p.bhh_v[1024 + j];
        float hp[4] = {0.f, 0.f, 0.f, 0.f};

        for (int t = 0; t < 80; ++t) {
            float gr[4], gz[4], gn[4];  // prefetch gi[t] (independent of flags)
            const float* gt = p.gi + (size_t)t * 98304;
#pragma unroll
            for (int r = 0; r < 4; ++r) {
                const float* gb = gt + (size_t)(b_ + r) * 1536;
                gr[r] = gb[j]; gz[r] = gb[512 + j]; gn[r] = gb[1024 + j];
            }
            f32x4 aR = z4, aZ = z4, aN = z4;
            if (t > 0) {
                flags_wait<1>(F_EO, t);
                mm3_s(p.eo + (size_t)(t - 1) * 32768, m0, Wlds, lane, aR, aZ, aN);
            }
            unsigned short* eoW = p.eo + (size_t)t * 32768;
#pragma unroll
            for (int r = 0; r < 4; ++r) {
                float rg = sigm(gr[r] + aR[r] + bhr);
                float zg = sigm(gz[r] + aZ[r] + bhz);
                float ng = tanh_f(gn[r] + rg * (aN[r] + bhn));
                float hn = (1.f - zg) * ng + zg * hp[r];
                hp[r] = hn;
                stg_b16_sc(eoW + (size_t)(b_ + r) * 512 + j, f2b(hn));
            }
            block_publish(F_EO + blk * 16, t + 1);
        }

        // ----- decoder h_v2 chain -----
        flags_wait<1>(F_EC, 80);  // hcf + hv2B[0] ready
        const float bir = p.bih_v[j], biz = p.bih_v[512 + j], bin_ = p.bih_v[1024 + j];
        for (int s = 0; s <= 30; ++s) {
            if (s > 0) flags_wait<1>(F_HV, s);
            f32x4 aR = z4, aZ = z4, aN = z4;
            mm3_s(p.hv2B + (size_t)s * 32768, m0, Wlds, lane, aR, aZ, aN);
            unsigned short* hw = p.hv2B + (size_t)(s + 1) * 32768;
            float* hwF = p.hv2F + (size_t)(s + 1) * 32768;
#pragma unroll
            for (int r = 0; r < 4; ++r) {
                float hpv = (s == 0) ? ldg_f32_sc(p.hcf + (size_t)(b_ + r) * 512 + j) : hp[r];
                float rg = sigm(bir + aR[r] + bhr);
                float zg = sigm(biz + aZ[r] + bhz);
                float ng = tanh_f(bin_ + rg * (aN[r] + bhn));
                float hn = (1.f - zg) * ng + zg * hpv;
                hp[r] = hn;
                stg_b16_sc(hw + (size_t)(b_ + r) * 512 + j, f2b(hn));
                stg_b32_sc(hwF + (size_t)(b_ + r) * 512 + j, hn);
            }
            block_publish(F_HV + blk * 16, s + 1);
        }

        // ----- loss (blocks 0..15: row b = blk*4+wave) -----
        if (blk < 16) {
            const int b = (blk << 2) | wave;
            scalar_wait<2>(S_LOG, 125);
            const float* lg = p.out + (size_t)b * 192000 + 186000;
            float m = -1e30f, sum = 0.f;
            for (int i = lane; i < 3000; i += 64) {
                union { unsigned long long u; float f[2]; } pr;
                pr.u = ldg_u64_sc(lg + 2 * i);
#pragma unroll
                for (int e = 0; e < 2; ++e) {
                    float v = pr.f[e];
                    float nm = fmaxf(m, v);
                    sum = sum * __expf(m - nm) + __expf(v - nm);
                    m = nm;
                }
            }
#pragma unroll
            for (int off = 32; off > 0; off >>= 1) {
                float m2 = __shfl_down(m, off);
                float s2 = __shfl_down(sum, off);
                float nm = fmaxf(m, m2);
                sum = sum * __expf(m - nm) + s2 * __expf(m2 - nm);
                m = nm;
            }
            if (lane == 0) {
                int yv = p.y[31 * 64 + b];
                float lgy = ldg_f32_sc(lg + yv);
                stg_b32_sc(p.lossP + b, (m + __logf(sum)) - lgy);
            }
            wave_add(S_LP);
            if (blk == 0 && wave == 0) {
                scalar_wait<1>(S_LP, 64);
                float v = ldg_f32_sc(p.lossP + lane);
#pragma unroll
                for (int off = 32; off > 0; off >>= 1) v += __shfl_down(v, off);
                if (lane == 0) p.out[12288000] = v * (1.f / 64.f);
            }
        }
    } else if (blk < 64) {
        // ================= group_c =================
        const int cid = blk - 32;
        const int j0 = cid * 16;
        const int j = j0 + l15;
        const int m0 = wave * 16;
        const int b_ = m0 + quad * 4;
#pragma unroll
        for (int g = 0; g < 3; ++g) {
            stage_swz(p.WchhB + (size_t)(g * 512 + j0) * 512, Wlds + g * WTILE);
            stage_swz(p.WhhcB + (size_t)(g * 512 + j0) * 512, Wlds + (3 + g) * WTILE);
        }
        __syncthreads();
        const float bcr = p.bih_c[j] + p.bhh_c[j];
        const float bcz = p.bih_c[512 + j] + p.bhh_c[512 + j];
        const float bin_ = p.bih_c[1024 + j];
        const float bhn = p.bhh_c[1024 + j];
        float hp[4] = {0.f, 0.f, 0.f, 0.f};

        for (int t = 0; t < 80; ++t) {
            flags_wait2<1>(F_EO, t + 1, F_EC, t);  // eo[t] ready; own group at step t
            const unsigned short* A1 = (t == 0) ? p.zeroB : ((t & 1) ? p.ecb0 : p.ecb1);
            unsigned short* ew = (t & 1) ? p.ecb1 : p.ecb0;
            f32x4 aR = z4, aZ = z4, aIN = z4, aHN = z4;
            mm6_s(p.eo + (size_t)t * 32768, A1, m0, Wlds, lane, aR, aZ, aIN, aHN);
#pragma unroll
            for (int r = 0; r < 4; ++r) {
                float rg = sigm(aR[r] + bcr);
                float zg = sigm(aZ[r] + bcz);
                float ng = tanh_f(aIN[r] + bin_ + rg * (aHN[r] + bhn));
                float hn = (1.f - zg) * ng + zg * hp[r];
                hp[r] = hn;
                unsigned short hb = f2b(hn);
                stg_b16_sc(ew + (size_t)(b_ + r) * 512 + j, hb);
                if (t == 79) {
                    stg_b16_sc(p.hv2B + (size_t)(b_ + r) * 512 + j, hb);
                    stg_b32_sc(p.hcf + (size_t)(b_ + r) * 512 + j, hn);
                }
            }
            block_publish(F_EC + cid * 16, t + 1);
        }

        // ----- decoder h_c (no inter-step chain) -----
        scalar_wait<4>(S_TR, 94);  // WcwT ready
        for (int s = 0; s <= 30; ++s) {
            // prefetch embedding rows for this step (y known in advance)
            float er[4], ez[4], en[4];
#pragma unroll
            for (int r = 0; r < 4; ++r) {
                const int yv = p.y[s * 64 + (b_ + r)];
                const unsigned short* em = p.WcwTB + (size_t)yv * 1536;
                er[r] = ldg_b16_sc(em + j);
                ez[r] = ldg_b16_sc(em + 512 + j);
                en[r] = ldg_b16_sc(em + 1024 + j);
            }
            flags_wait<1>(F_HV, s + 1);
            const unsigned short* hv = p.hv2B + (size_t)(s + 1) * 32768;
            const float* hvF = p.hv2F + (size_t)(s + 1) * 32768;
            f32x4 aR = z4, aZ = z4, aIN = z4, aHN = z4;
            mm6_s(hv, hv, m0, Wlds, lane, aR, aZ, aIN, aHN);
            unsigned short* hc = p.hcdB + (size_t)s * 32768;
#pragma unroll
            for (int r = 0; r < 4; ++r) {
                float rg = sigm(aR[r] + er[r] + bcr);
                float zg = sigm(aZ[r] + ez[r] + bcz);
                float ng = tanh_f(aIN[r] + en[r] + bin_ + rg * (aHN[r] + bhn));
                float hpv = ldg_f32_sc(hvF + (size_t)(b_ + r) * 512 + j);
                stg_b16_sc(hc + (size_t)(b_ + r) * 512 + j, f2b((1.f - zg) * ng + zg * hpv));
            }
            block_publish(F_HC + cid * 16, s + 1);
        }
    } else {
        // ================= group_o =================
        const int bo = blk - 64;          // 0..124
        const int w0 = bo * 48;           // 48 Wout cols each
#pragma unroll
        for (int tl = 0; tl < 3; ++tl)
            stage_swz(p.WoutB + (size_t)(w0 + tl * 16) * 512, Wlds + tl * WTILE);
        __syncthreads();

        // --- WcwT transpose during encoder slack: block bo handles cols bo*64..+63 ---
        if (bo < 94) {
            float* tile = (float*)(Wlds + 24576);  // 64x65 fp32 scratch after Wout tiles
            const int w0t = bo * 64;
            const int tx = threadIdx.x & 63, ty = threadIdx.x >> 6;
            for (int gt = 0; gt < 24; ++gt) {
                const int g0 = gt * 64;
                __syncthreads();
                for (int r = ty; r < 64; r += 4) {
                    int w = w0t + tx;
                    tile[r * 65 + tx] = (w < 6000) ? p.Wc[(size_t)(g0 + r) * 6512 + 512 + w] : 0.f;
                }
                __syncthreads();
                for (int r = ty; r < 64; r += 4) {
                    int w = w0t + r;
                    if (w < 6000)
                        stg_b16_sc(p.WcwTB + (size_t)w * 1536 + g0 + tx, f2b(tile[tx * 65 + r]));
                }
            }
            asm volatile("s_waitcnt vmcnt(0)" ::: "memory");
            __syncthreads();
            if (threadIdx.x == 0)
                __hip_atomic_fetch_add(S_TR, 1, __ATOMIC_RELAXED, __HIP_MEMORY_SCOPE_AGENT);
        }

        // --- logits ---
        const int m0 = wave * 16;
        const int b_ = m0 + quad * 4;
        float bo_[3];
#pragma unroll
        for (int tl = 0; tl < 3; ++tl) bo_[tl] = p.bout[w0 + tl * 16 + l15];

        for (int s = 0; s <= 30; ++s) {
            flags_wait<2>(F_HC, s + 1);
            const unsigned short* ab =
                p.hcdB + (size_t)s * 32768 + (size_t)(m0 + l15) * 512 + quad * 8;
            s16x8 af[16];
#pragma unroll
            for (int c = 0; c < 16; ++c) af[c] = ldA_sc(ab + c * 32);
#pragma unroll
            for (int tl = 0; tl < 3; ++tl) {
                f32x4 acc = z4;
#pragma unroll
                for (int c = 0; c < 16; ++c) acc = MFMA_B16(af[c], WF(Wlds, tl, c, lane), acc);
#pragma unroll
                for (int r = 0; r < 4; ++r)
                    stg_b32_sc(p.out + (size_t)(b_ + r) * 192000 + (size_t)(s + 1) * 6000 +
                                   w0 + tl * 16 + l15,
                               acc[r] + bo_[tl]);
            }
        }
        asm volatile("s_waitcnt vmcnt(0)" ::: "memory");
        __syncthreads();
        if (threadIdx.x == 0)
            __hip_atomic_fetch_add(S_LOG, 1, __ATOMIC_RELAXED, __HIP_MEMORY_SCOPE_AGENT);
    }
}

// ---------- host ----------
extern "C" void kernel_launch(void* const* d_in, const int* in_sizes, int n_in,
                              void* d_out, int out_size, void* d_ws, size_t ws_size,
                              hipStream_t stream) {
    const float* x     = (const float*)d_in[0];
    const int*   y     = (const int*)d_in[1];
    const float* Wih_v = (const float*)d_in[2];
    const float* Whh_v = (const float*)d_in[3];
    const float* bih_v = (const float*)d_in[4];
    const float* bhh_v = (const float*)d_in[5];
    const float* Wih_c = (const float*)d_in[6];
    const float* Whh_c = (const float*)d_in[7];
    const float* bih_c = (const float*)d_in[8];
    const float* bhh_c = (const float*)d_in[9];
    const float* Wout  = (const float*)d_in[10];
    const float* bout  = (const float*)d_in[11];
    float* out = (float*)d_out;

    char* w = (char*)d_ws;
    size_t o = 0;
    auto alloc = [&](size_t bytes) -> void* {
        void* p = (void*)(w + o);
        o += (bytes + 255) & ~(size_t)255;
        return p;
    };
    float*          gi    = (float*)alloc(7864320ull * 4);
    unsigned short* xB    = (unsigned short*)alloc(20971520ull * 2);
    unsigned short* WihB  = (unsigned short*)alloc(6291456ull * 2);
    unsigned short* WhhvB = (unsigned short*)alloc(786432ull * 2);
    unsigned short* WhhcB = (unsigned short*)alloc(786432ull * 2);
    unsigned short* WchhB = (unsigned short*)alloc(786432ull * 2);
    unsigned short* WoutB = (unsigned short*)alloc(3072000ull * 2);
    unsigned short* WcwTB = (unsigned short*)alloc(9216000ull * 2);
    unsigned short* eo    = (unsigned short*)alloc(80ull * 32768 * 2);
    unsigned short* hv2B  = (unsigned short*)alloc(32ull * 32768 * 2);
    float*          hv2F  = (float*)alloc(32ull * 32768 * 4);
    unsigned short* hcdB  = (unsigned short*)alloc(31ull * 32768 * 2);
    unsigned short* ecb0  = (unsigned short*)alloc(32768ull * 2);
    unsigned short* ecb1  = (unsigned short*)alloc(32768ull * 2);
    unsigned short* zeroB = (unsigned short*)alloc(32768ull * 2);
    float*          hcf   = (float*)alloc(32768ull * 4);
    float*          lossP = (float*)alloc(64ull * 4);
    int*            ctrs  = (int*)alloc(4096ull * 4);
    if (o > ws_size) return;

    prep_kernel<<<512, 256, 0, stream>>>(x, Wih_v, Whh_v, Whh_c, Wih_c, Wout, xB, WihB,
                                         WhhvB, WhhcB, WchhB, WoutB, zeroB, ctrs, out);
    gemm1_kernel<<<480, 256, 0, stream>>>(xB, WihB, bih_v, gi);

    SeqParams p;
    p.bih_v = bih_v; p.bhh_v = bhh_v; p.bih_c = bih_c; p.bhh_c = bhh_c;
    p.bout = bout; p.y = y; p.gi = gi; p.Wc = Wih_c; p.out = out;
    p.WhhvB = WhhvB; p.WhhcB = WhhcB; p.WchhB = WchhB; p.WoutB = WoutB; p.WcwTB = WcwTB;
    p.eo = eo; p.hv2B = hv2B; p.hv2F = hv2F; p.hcdB = hcdB;
    p.ecb0 = ecb0; p.ecb1 = ecb1; p.zeroB = zeroB;
    p.hcf = hcf; p.lossP = lossP; p.ctr = ctrs;
    void* args[] = {&p};
    hipLaunchCooperativeKernel((void*)seq_kernel, dim3(189), dim3(256), args, 0, stream);
}